// Round 12
// baseline (580.799 us; speedup 1.0000x reference)
//
#include <hip/hip_runtime.h>
#include <math.h>

constexpr int N  = 60000;
constexpr int F  = 256;
constexpr int H  = 128;
constexpr int C  = 256;
constexpr int E  = 600000;
constexpr int ET = 1500;
constexpr int NB = (N + 1023) / 1024;  // 59 scan blocks
constexpr int SPL = 8;                 // bu softmax splits per cluster
constexpr int PB  = 16;                // pooling blocks

typedef __attribute__((ext_vector_type(8))) short short8;
typedef __attribute__((ext_vector_type(4))) float f32x4;

__device__ __forceinline__ unsigned short f2b(float f) {  // fp32 -> bf16 (RNE)
  unsigned int u = __float_as_uint(f);
  return (unsigned short)((u + 0x7FFFu + ((u >> 16) & 1u)) >> 16);
}
__device__ __forceinline__ float b2f(unsigned short b) {
  return __uint_as_float(((unsigned int)b) << 16);
}

// ---------------- histograms (cell-dst degree + cluster counts) ----------------
__global__ void hg_hist(const int* __restrict__ cdst, int* __restrict__ deg,
                        const int* __restrict__ lab, int* __restrict__ ccnt) {
  int e = blockIdx.x * 256 + threadIdx.x;
  if (e < E) atomicAdd(&deg[cdst[e]], 1);
  if (e < N) atomicAdd(&ccnt[lab[e]], 1);
}

// ---------------- multi-block scan ----------------
__global__ __launch_bounds__(256) void hg_scan1(const int* __restrict__ deg, int* __restrict__ off,
                                                int* __restrict__ btot, int n) {
  int b = blockIdx.x, t = threadIdx.x;
  int i0 = b * 1024 + t * 4;
  __shared__ int sums[256];
  int d0 = 0, d1 = 0, d2 = 0, d3 = 0;
  if (i0 + 3 < n) {
    int4 dd = *(const int4*)&deg[i0];
    d0 = dd.x; d1 = dd.y; d2 = dd.z; d3 = dd.w;
  } else {
    if (i0     < n) d0 = deg[i0];
    if (i0 + 1 < n) d1 = deg[i0 + 1];
    if (i0 + 2 < n) d2 = deg[i0 + 2];
    if (i0 + 3 < n) d3 = deg[i0 + 3];
  }
  int s = d0 + d1 + d2 + d3;
  sums[t] = s;
  __syncthreads();
  for (int ofs = 1; ofs < 256; ofs <<= 1) {
    int v = (t >= ofs) ? sums[t - ofs] : 0;
    __syncthreads();
    sums[t] += v;
    __syncthreads();
  }
  int excl = sums[t] - s;
  if (t == 255) btot[b] = sums[t];
  int run = excl;
  if (i0     < n) off[i0]     = run; run += d0;
  if (i0 + 1 < n) off[i0 + 1] = run; run += d1;
  if (i0 + 2 < n) off[i0 + 2] = run; run += d2;
  if (i0 + 3 < n) off[i0 + 3] = run;
}

// block0: scan of btot; block1: cluster-count scan; block2: tissue CSR + dinv
__global__ __launch_bounds__(256) void hg_scan2_setup(int* __restrict__ btot, int* __restrict__ off,
                                                      const int* __restrict__ ccnt, int* __restrict__ coff,
                                                      const int* __restrict__ tsrc, const int* __restrict__ tdst,
                                                      int* __restrict__ toff, int* __restrict__ tlist,
                                                      float* __restrict__ dinv) {
  __shared__ int sa[256], sb[256], sc2[256];
  int t = threadIdx.x;
  if (blockIdx.x == 0) {
    if (t < 64) sa[t] = (t < NB) ? btot[t] : 0;
    __syncthreads();
    if (t == 0) {
      int r = 0;
      for (int i = 0; i < NB; ++i) { int v = sa[i]; sa[i] = r; r += v; }
      off[N] = r;
    }
    __syncthreads();
    if (t < NB) btot[t] = sa[t];
  } else if (blockIdx.x == 1) {
    int v0 = ccnt[t];
    sa[t] = v0;
    __syncthreads();
    for (int ofs = 1; ofs < 256; ofs <<= 1) {
      int v = (t >= ofs) ? sa[t - ofs] : 0;
      __syncthreads();
      sa[t] += v;
      __syncthreads();
    }
    coff[t + 1] = sa[t];
    if (t == 0) coff[0] = 0;
  } else {
    sa[t] = 0;
    __syncthreads();
    for (int e = t; e < ET; e += 256) atomicAdd(&sa[tdst[e]], 1);
    __syncthreads();
    int v = sa[t];
    dinv[t] = rsqrtf((float)(v + 1));
    sb[t] = v;
    __syncthreads();
    for (int ofs = 1; ofs < 256; ofs <<= 1) {
      int u = (t >= ofs) ? sb[t - ofs] : 0;
      __syncthreads();
      sb[t] += u;
      __syncthreads();
    }
    toff[t + 1] = sb[t];
    if (t == 0) toff[0] = 0;
    sc2[t] = sb[t] - v;
    __syncthreads();
    for (int e = t; e < ET; e += 256) {
      int d = tdst[e];
      int p = atomicAdd(&sc2[d], 1);
      tlist[p] = tsrc[e];
    }
  }
}

__global__ void hg_scan3(int* __restrict__ off, const int* __restrict__ btot, int n) {
  int b = blockIdx.x;
  int addv = btot[b];
  int i0 = b * 1024 + threadIdx.x * 4;
#pragma unroll
  for (int r = 0; r < 4; ++r)
    if (i0 + r < n) off[i0 + r] += addv;
}

// merged: cell-edge CSR scatter + cluster-list scatter
__global__ void hg_scatter(const int* __restrict__ csrc, const int* __restrict__ cdst,
                           const int* __restrict__ off, int* __restrict__ cur, int* __restrict__ csr,
                           const int* __restrict__ lab, const int* __restrict__ coff,
                           int* __restrict__ ccur, int* __restrict__ list) {
  int e = blockIdx.x * 256 + threadIdx.x;
  if (e < E) {
    int d = cdst[e];
    int p = atomicAdd(&cur[d], 1);
    csr[off[d] + p] = csrc[e];
  }
  if (e < N) {
    int c = lab[e];
    int p = atomicAdd(&ccur[c], 1);
    list[coff[c] + p] = e;
  }
}

// ---------------- prep: 8 transposes + pc0(bf16) + pc1 + qs/qd columns (grid y = job) ----------------
struct TJob { const float* src; float* dst; int SR; int SC; int dld; };
struct PrepArgs {
  TJob j[8];
  const float* gatW1; const float* Wcp; const float* bcp; short* Wcompb; float* bcomp;
  const float* tdWo; const float* tdWv; const float* tdbv; const float* tdbo;
  float* A_td; float* Wcat_t; float* bcat;
  const float* avs; const float* avd; float* sbias;
};

__global__ __launch_bounds__(256) void hg_prep1(PrepArgs a) {
  int y = blockIdx.y, t = threadIdx.x;
  if (y < 8) {
    TJob jb = a.j[y];
    int total = jb.SR * jb.SC;
    for (int idx = blockIdx.x * 256 + t; idx < total; idx += gridDim.x * 256) {
      int r = idx / jb.SC, c = idx - r * jb.SC;
      jb.dst[(size_t)c * jb.dld + r] = jb.src[idx];
    }
  } else if (y == 8) {
    // pc0: Wcomp[j][k] = sum_m gatW1[j][m]*Wcp[m][k]  (bf16, j-major for MFMA B frags)
    int j = blockIdx.x, k = t;
    float acc = 0.f;
#pragma unroll 4
    for (int m = 0; m < 128; ++m) acc = fmaf(a.gatW1[j * 128 + m], a.Wcp[m * 256 + k], acc);
    a.Wcompb[(size_t)j * 256 + k] = (short)f2b(acc);
    if (k == 0) {
      float b = 0.f;
      for (int m = 0; m < 128; ++m) b = fmaf(a.gatW1[j * 128 + m], a.bcp[m], b);
      a.bcomp[j] = b;
    }
  } else if (y == 9) {
    if (blockIdx.x >= 64) return;
    int j = blockIdx.x * 2 + (t >> 7), k = t & 127;
    float acc = 0.f;
#pragma unroll 4
    for (int p = 0; p < 128; ++p) acc = fmaf(a.tdWo[j * 128 + p], a.tdWv[p * 128 + k], acc);
    a.A_td[j * 128 + k] = acc;
    a.Wcat_t[k * 896 + j] = acc;
    if (k == 0) {
      float b = 0.f;
      for (int p = 0; p < 128; ++p) b = fmaf(a.tdWo[j * 128 + p], a.tdbv[p], b);
      a.bcat[j] = b + a.tdbo[j];
    }
  } else {
    // y == 10: qs/qd columns 128..143 of Wcompb  (o_s = feat·qs_h + cs_h)
    if (blockIdx.x >= 16) return;
    __shared__ float u[128];
    int dir = blockIdx.x >> 3, h = blockIdx.x & 7;
    const float* av = (dir == 0 ? a.avs : a.avd) + h * 16;
    if (t < 128) {
      float s = 0.f;
#pragma unroll
      for (int j = 0; j < 16; ++j) s = fmaf(a.gatW1[(size_t)(h * 16 + j) * 128 + t], av[j], s);
      u[t] = s;
    }
    __syncthreads();
    float q = 0.f;
#pragma unroll 4
    for (int m = 0; m < 128; ++m) q = fmaf(u[m], a.Wcp[m * 256 + t], q);
    a.Wcompb[(size_t)(128 + dir * 8 + h) * 256 + t] = (short)f2b(q);
    if (t == 0) {
      float cs = 0.f;
      for (int m = 0; m < 128; ++m) cs = fmaf(u[m], a.bcp[m], cs);
      a.sbias[dir * 8 + h] = cs;
    }
  }
}

__global__ __launch_bounds__(256) void hg_pc2b(const float* __restrict__ Wih, const float* __restrict__ bih,
                                               const float* __restrict__ Whh, const float* __restrict__ bhh,
                                               const float* __restrict__ A_td, float* __restrict__ Wcat_t,
                                               float* __restrict__ bcat) {
  int jj = blockIdx.x * 2 + (threadIdx.x >> 7), k = threadIdx.x & 127;
  const float* coef;
  float extra, bb;
  int dcol, j;
  if (jj < 384) {
    j = jj; coef = Wih + (size_t)j * 256; extra = Wih[(size_t)j * 256 + 128 + k]; dcol = 128 + j; bb = bih[j];
  } else {
    j = jj - 384; coef = Whh + (size_t)j * 128; extra = 0.f; dcol = 512 + j; bb = bhh[j];
  }
  float a = 0.f;
#pragma unroll 4
  for (int m = 0; m < 128; ++m) a = fmaf(coef[m], A_td[m * 128 + k], a);
  Wcat_t[k * 896 + dcol] = a + extra;
  if (k == 0) {
    float b = 0.f;
    for (int m = 0; m < 128; ++m) b = fmaf(coef[m], bcat[m], b);
    bcat[dcol] = b + bb;
  }
}

// ---------------- MFMA bf16 GEMM: 64-row tile, FULL-K A preload, L2-only inner loop ----------------
__global__ __launch_bounds__(256) void hg_gemm_coef(
    const float* __restrict__ A, int M, int rtiles,
    const short* __restrict__ Wb,          // bf16 [144][256] j-major (128 out + 16 coef cols)
    const float* __restrict__ bias,        // [128]
    const float* __restrict__ sbias,       // [16]
    unsigned short* __restrict__ outp,     // bf16 [M][128]
    float* __restrict__ o_s, float* __restrict__ o_d,  // [M][8] each
    const int* __restrict__ list, const int* __restrict__ coff,
    const float* __restrict__ Wtpt, const float* __restrict__ btp, float* __restrict__ tish) {
  __shared__ float mrow[256];
  const int t = threadIdx.x;

  if (blockIdx.x >= rtiles) {
    // ---- tissue init: per-cluster mean + projection (fp32) ----
    int c = blockIdx.x - rtiles;
    int s0 = coff[c], n = coff[c + 1] - s0;
    float acc = 0.f;
#pragma unroll 4
    for (int i = 0; i < n; ++i) acc += A[(size_t)list[s0 + i] * F + t];
    mrow[t] = acc / fmaxf((float)n, 1.f);
    __syncthreads();
    if (t < 128) {
      float a = btp[t];
#pragma unroll 4
      for (int k = 0; k < 256; ++k) a = fmaf(mrow[k], Wtpt[k * 128 + t], a);
      tish[c * 128 + t] = a;
    }
    return;
  }

  const int w = t >> 6, l = t & 63;
  const int li = l & 15, lk = l >> 4;
  const int rbase = blockIdx.x * 64 + w * 16;
  const int row = rbase + li;
  const bool v = row < M;
  const float* ap = A + (size_t)row * 256 + lk * 8;

  // full-K A preload: 16 independent HBM loads, converted once to 8 bf16 fragments
  short8 af[8];
#pragma unroll
  for (int kc8 = 0; kc8 < 8; ++kc8) {
    short8 a = {0, 0, 0, 0, 0, 0, 0, 0};
    if (v) {
      float4 x = *(const float4*)(ap + kc8 * 32);
      float4 y = *(const float4*)(ap + kc8 * 32 + 4);
      a[0] = (short)f2b(x.x); a[1] = (short)f2b(x.y); a[2] = (short)f2b(x.z); a[3] = (short)f2b(x.w);
      a[4] = (short)f2b(y.x); a[5] = (short)f2b(y.y); a[6] = (short)f2b(y.z); a[7] = (short)f2b(y.w);
    }
    af[kc8] = a;
  }

  f32x4 zero = {0.f, 0.f, 0.f, 0.f};
  f32x4 acc[9];
#pragma unroll
  for (int ct = 0; ct < 9; ++ct) acc[ct] = zero;

  // inner loop: only L2-resident B loads + MFMAs (9 independent acc chains)
#pragma unroll
  for (int kc8 = 0; kc8 < 8; ++kc8) {
#pragma unroll
    for (int ct = 0; ct < 9; ++ct) {
      short8 bf = *(const short8*)&Wb[(size_t)(ct * 16 + li) * 256 + kc8 * 32 + lk * 8];
      acc[ct] = __builtin_amdgcn_mfma_f32_16x16x32_bf16(af[kc8], bf, acc[ct], 0, 0, 0);
    }
  }

  // epilogue: bias + bf16 store (output rows rbase + lk*4 + r, col ct*16+li)
#pragma unroll
  for (int ct = 0; ct < 8; ++ct) {
    float bj = bias[ct * 16 + li];
#pragma unroll
    for (int r = 0; r < 4; ++r) {
      int gm = rbase + lk * 4 + r;
      if (gm < M) outp[(size_t)gm * 128 + ct * 16 + li] = f2b(acc[ct][r] + bj);
    }
  }
  // coef tile -> split a_s / a_d
  {
    float sb = sbias[li];
#pragma unroll
    for (int r = 0; r < 4; ++r) {
      int gm = rbase + lk * 4 + r;
      if (gm < M) {
        float vv = acc[8][r] + sb;
        if (li < 8) o_s[(size_t)gm * 8 + li] = vv;
        else        o_d[(size_t)gm * 8 + (li - 8)] = vv;
      }
    }
  }
}

// ---------------- GAT aggregation L1: one WAVE per node, bf16 gathers ----------------
#define GMAXE 64
__global__ __launch_bounds__(256) void hg_gat_agg(
    const unsigned short* __restrict__ hproj, const float* __restrict__ a_s,
    const float* __restrict__ a_d,
    const int* __restrict__ off, const int* __restrict__ csr,
    const float* __restrict__ bias, unsigned short* __restrict__ outh,
    const float* __restrict__ qk, const float* __restrict__ qb,
    const int* __restrict__ lab, const int* __restrict__ nodelist,
    float* __restrict__ satt, int nNodes) {
  const int wid = threadIdx.x >> 6;
  const int l = threadIdx.x & 63;
  const int gid = blockIdx.x * 4 + wid;
  __shared__ int srcs_s[4][GMAXE];
  __shared__ float w_s[4][GMAXE][8];
  if (gid >= nNodes) return;
  const int node = nodelist[gid];
  int* srcs = srcs_s[wid];
  float (*wls)[8] = w_s[wid];
  const int o0 = off[node], deg = off[node + 1] - o0;
  const int cl = lab[node];
  const int hsc = l & 7;
  const int q4 = l & 31;
  const int sub = l >> 5;
  const int hq = q4 >> 2;
  const float adh = a_d[(size_t)node * 8 + hsc];
  const float ash = a_s[(size_t)node * 8 + hsc];
  float msc = -INFINITY, zsc = 0.f;
  float4 acc = make_float4(0.f, 0.f, 0.f, 0.f);
  const ushort4* hp4 = (const ushort4*)hproj;

  for (int cb = 0; cb < deg; cb += GMAXE) {
    const int len = min(GMAXE, deg - cb);
    if (l < len) srcs[l] = csr[o0 + cb + l];
    asm volatile("s_waitcnt lgkmcnt(0)" ::: "memory");
    float lm = -INFINITY;
    for (int base = 0; base < len; base += 8) {
      int e = base + (l >> 3);
      if (e < len) {
        float sc = a_s[(size_t)srcs[e] * 8 + hsc] + adh;
        sc = sc > 0.f ? sc : 0.2f * sc;
        wls[e][hsc] = sc;
        lm = fmaxf(lm, sc);
      }
    }
    lm = fmaxf(lm, __shfl_xor(lm, 8));
    lm = fmaxf(lm, __shfl_xor(lm, 16));
    lm = fmaxf(lm, __shfl_xor(lm, 32));
    float mnew = fmaxf(msc, lm);
    float rs = __expf(msc - mnew);
    float zc = 0.f;
    asm volatile("s_waitcnt lgkmcnt(0)" ::: "memory");
    for (int base = 0; base < len; base += 8) {
      int e = base + (l >> 3);
      if (e < len) {
        float wv = __expf(wls[e][hsc] - mnew);
        wls[e][hsc] = wv;
        zc += wv;
      }
    }
    asm volatile("s_waitcnt lgkmcnt(0)" ::: "memory");
    zc += __shfl_xor(zc, 8); zc += __shfl_xor(zc, 16); zc += __shfl_xor(zc, 32);
    zsc = zsc * rs + zc;
    msc = mnew;
    float rsa = __shfl(rs, hq);
    acc.x *= rsa; acc.y *= rsa; acc.z *= rsa; acc.w *= rsa;
    for (int e = sub; e < len; e += 2) {
      float wv = wls[e][hq];
      ushort4 hv = hp4[(size_t)srcs[e] * 32 + q4];
      acc.x = fmaf(wv, b2f(hv.x), acc.x);
      acc.y = fmaf(wv, b2f(hv.y), acc.y);
      acc.z = fmaf(wv, b2f(hv.z), acc.z);
      acc.w = fmaf(wv, b2f(hv.w), acc.w);
    }
  }
  float ssl = ash + adh;
  ssl = ssl > 0.f ? ssl : 0.2f * ssl;
  float mnew = fmaxf(msc, ssl);
  float rs = __expf(msc - mnew);
  float wsl = __expf(ssl - mnew);
  zsc = zsc * rs + wsl;
  float rsa = __shfl(rs, hq);
  float wsa = __shfl(wsl, hq);
  float zh = __shfl(zsc, hq);
  acc.x *= rsa; acc.y *= rsa; acc.z *= rsa; acc.w *= rsa;
  acc.x += __shfl_xor(acc.x, 32);
  acc.y += __shfl_xor(acc.y, 32);
  acc.z += __shfl_xor(acc.z, 32);
  acc.w += __shfl_xor(acc.w, 32);
  ushort4 hvs = hp4[(size_t)node * 32 + q4];
  acc.x = fmaf(wsa, b2f(hvs.x), acc.x);
  acc.y = fmaf(wsa, b2f(hvs.y), acc.y);
  acc.z = fmaf(wsa, b2f(hvs.z), acc.z);
  acc.w = fmaf(wsa, b2f(hvs.w), acc.w);
  float inv = 1.f / zh;
  float4 bv4 = *(const float4*)&bias[q4 * 4];
  float4 o;
  o.x = acc.x * inv + bv4.x;
  o.y = acc.y * inv + bv4.y;
  o.z = acc.z * inv + bv4.z;
  o.w = acc.w * inv + bv4.w;
  o.x = o.x > 0.f ? o.x : __expf(o.x) - 1.f;
  o.y = o.y > 0.f ? o.y : __expf(o.y) - 1.f;
  o.z = o.z > 0.f ? o.z : __expf(o.z) - 1.f;
  o.w = o.w > 0.f ? o.w : __expf(o.w) - 1.f;
  if (sub == 0) {
    ushort4 ov = make_ushort4(f2b(o.x), f2b(o.y), f2b(o.z), f2b(o.w));
    ((ushort4*)outh)[(size_t)node * 32 + q4] = ov;
  }

  // s_att epilogue (qk L2-hot via clu_list ordering)
  const float4* qk4 = (const float4*)(qk + (size_t)cl * 1024);
  float p0, p1, p2, p3;
  {
    float4 qv0 = qk4[(sub * 4 + 0) * 32 + q4];
    float4 qv1 = qk4[(sub * 4 + 1) * 32 + q4];
    float4 qv2 = qk4[(sub * 4 + 2) * 32 + q4];
    float4 qv3 = qk4[(sub * 4 + 3) * 32 + q4];
    p0 = o.x * qv0.x + o.y * qv0.y + o.z * qv0.z + o.w * qv0.w;
    p1 = o.x * qv1.x + o.y * qv1.y + o.z * qv1.z + o.w * qv1.w;
    p2 = o.x * qv2.x + o.y * qv2.y + o.z * qv2.z + o.w * qv2.w;
    p3 = o.x * qv3.x + o.y * qv3.y + o.z * qv3.z + o.w * qv3.w;
  }
  int b4f = (l >> 4) & 1, b3f = (l >> 3) & 1;
  float snd0 = b4f ? p0 : p2, snd1 = b4f ? p1 : p3;
  float kp0  = b4f ? p2 : p0, kp1  = b4f ? p3 : p1;
  kp0 += __shfl_xor(snd0, 16);
  kp1 += __shfl_xor(snd1, 16);
  float snd = b3f ? kp0 : kp1;
  float kp  = b3f ? kp1 : kp0;
  kp += __shfl_xor(snd, 8);
  kp += __shfl_xor(kp, 4);
  kp += __shfl_xor(kp, 2);
  kp += __shfl_xor(kp, 1);
  int h = sub * 4 + b4f * 2 + b3f;
  if ((l & 7) == 0) satt[(size_t)node * 8 + h] = kp + qb[cl * 8 + h];
}

// ---------------- pairwise softmax table for layer 2 ----------------
__global__ __launch_bounds__(256) void hg_ttab(const float* __restrict__ a_sc, const float* __restrict__ a_dc,
                                               float* __restrict__ T) {
  int cd = blockIdx.x, cs = threadIdx.x;
  __shared__ float as[256][8];
  __shared__ float mx[8];
#pragma unroll
  for (int h = 0; h < 8; ++h) as[cs][h] = a_sc[cs * 8 + h];
  __syncthreads();
  if (cs < 8) {
    float m = -INFINITY;
    for (int i = 0; i < 256; ++i) m = fmaxf(m, as[i][cs]);
    mx[cs] = m;
  }
  __syncthreads();
  float* Trow = T + ((size_t)cd * 256 + cs) * 8;
#pragma unroll
  for (int h = 0; h < 8; ++h) {
    float ad = a_dc[cd * 8 + h];
    float s = as[cs][h] + ad;
    s = s > 0.f ? s : 0.2f * s;
    float sm = mx[h] + ad;
    sm = sm > 0.f ? sm : 0.2f * sm;
    Trow[h] = __expf(s - sm);
  }
}

// ---------------- GAT aggregation L2: table-based ----------------
__global__ __launch_bounds__(256) void hg_gat_agg2(
    const unsigned short* __restrict__ hproj,   // [C][128] bf16
    const float* __restrict__ T,                // [256][256][8]
    const int* __restrict__ lab, const int* __restrict__ off, const int* __restrict__ csr,
    const float* __restrict__ bias, unsigned short* __restrict__ outh,
    const float* __restrict__ qk, const float* __restrict__ qb,
    const int* __restrict__ nodelist, float* __restrict__ satt, int nNodes) {
  const int wid = threadIdx.x >> 6;
  const int l = threadIdx.x & 63;
  const int gid = blockIdx.x * 4 + wid;
  __shared__ int srcs_s[4][GMAXE];
  if (gid >= nNodes) return;
  const int node = nodelist[gid];
  int* srcs = srcs_s[wid];
  const int o0 = off[node], deg = off[node + 1] - o0;
  const int cd = lab[node];
  const int q4 = l & 31;
  const int sub = l >> 5;
  const int hq = q4 >> 2;
  const float* Trow = T + (size_t)cd * 2048;
  const ushort4* hp4 = (const ushort4*)hproj;
  float4 acc = make_float4(0.f, 0.f, 0.f, 0.f);
  float z = 0.f;

  for (int cb = 0; cb < deg; cb += GMAXE) {
    const int len = min(GMAXE, deg - cb);
    if (l < len) srcs[l] = lab[csr[o0 + cb + l]];
    asm volatile("s_waitcnt lgkmcnt(0)" ::: "memory");
    for (int e = sub; e < len; e += 2) {
      int cs = srcs[e];
      float tw = Trow[cs * 8 + hq];
      ushort4 hv = hp4[(size_t)cs * 32 + q4];
      acc.x = fmaf(tw, b2f(hv.x), acc.x);
      acc.y = fmaf(tw, b2f(hv.y), acc.y);
      acc.z = fmaf(tw, b2f(hv.z), acc.z);
      acc.w = fmaf(tw, b2f(hv.w), acc.w);
      z += tw;
    }
    asm volatile("s_waitcnt lgkmcnt(0)" ::: "memory");
  }
  acc.x += __shfl_xor(acc.x, 32);
  acc.y += __shfl_xor(acc.y, 32);
  acc.z += __shfl_xor(acc.z, 32);
  acc.w += __shfl_xor(acc.w, 32);
  z += __shfl_xor(z, 32);
  {
    float tw = Trow[cd * 8 + hq];
    ushort4 hv = hp4[(size_t)cd * 32 + q4];
    acc.x = fmaf(tw, b2f(hv.x), acc.x);
    acc.y = fmaf(tw, b2f(hv.y), acc.y);
    acc.z = fmaf(tw, b2f(hv.z), acc.z);
    acc.w = fmaf(tw, b2f(hv.w), acc.w);
    z += tw;
  }
  float inv = 1.f / z;
  float4 bv4 = *(const float4*)&bias[q4 * 4];
  float4 o;
  o.x = acc.x * inv + bv4.x;
  o.y = acc.y * inv + bv4.y;
  o.z = acc.z * inv + bv4.z;
  o.w = acc.w * inv + bv4.w;
  o.x = o.x > 0.f ? o.x : __expf(o.x) - 1.f;
  o.y = o.y > 0.f ? o.y : __expf(o.y) - 1.f;
  o.z = o.z > 0.f ? o.z : __expf(o.z) - 1.f;
  o.w = o.w > 0.f ? o.w : __expf(o.w) - 1.f;
  if (sub == 0) {
    ushort4 ov = make_ushort4(f2b(o.x), f2b(o.y), f2b(o.z), f2b(o.w));
    ((ushort4*)outh)[(size_t)node * 32 + q4] = ov;
  }

  const float4* qk4 = (const float4*)(qk + (size_t)cd * 1024);
  float p0, p1, p2, p3;
  {
    float4 qv0 = qk4[(sub * 4 + 0) * 32 + q4];
    float4 qv1 = qk4[(sub * 4 + 1) * 32 + q4];
    float4 qv2 = qk4[(sub * 4 + 2) * 32 + q4];
    float4 qv3 = qk4[(sub * 4 + 3) * 32 + q4];
    p0 = o.x * qv0.x + o.y * qv0.y + o.z * qv0.z + o.w * qv0.w;
    p1 = o.x * qv1.x + o.y * qv1.y + o.z * qv1.z + o.w * qv1.w;
    p2 = o.x * qv2.x + o.y * qv2.y + o.z * qv2.z + o.w * qv2.w;
    p3 = o.x * qv3.x + o.y * qv3.y + o.z * qv3.z + o.w * qv3.w;
  }
  int b4f = (l >> 4) & 1, b3f = (l >> 3) & 1;
  float snd0 = b4f ? p0 : p2, snd1 = b4f ? p1 : p3;
  float kp0  = b4f ? p2 : p0, kp1  = b4f ? p3 : p1;
  kp0 += __shfl_xor(snd0, 16);
  kp1 += __shfl_xor(snd1, 16);
  float snd = b3f ? kp0 : kp1;
  float kp  = b3f ? kp1 : kp0;
  kp += __shfl_xor(snd, 8);
  kp += __shfl_xor(kp, 4);
  kp += __shfl_xor(kp, 2);
  kp += __shfl_xor(kp, 1);
  int h = sub * 4 + b4f * 2 + b3f;
  if ((l & 7) == 0) satt[(size_t)node * 8 + h] = kp + qb[cd * 8 + h];
}

// ---------------- tissue GCN + q projection + qk/qb tables ----------------
__global__ __launch_bounds__(128) void hg_gcn_q(const float* __restrict__ tin, const int* __restrict__ toff,
                                                const int* __restrict__ tlist, const float* __restrict__ dinv,
                                                const float* __restrict__ gt, const float* __restrict__ gcnb,
                                                const float* __restrict__ Wqt, const float* __restrict__ bq,
                                                const float* __restrict__ Wk, const float* __restrict__ bk,
                                                float* __restrict__ qk, float* __restrict__ qb) {
  int c = blockIdx.x, t = threadIdx.x;
  __shared__ float xa[128], trow[128], qrow[128];
  float dc = dinv[c];
  float acc = tin[c * 128 + t] * dc * dc;
  int s0 = toff[c], s1 = toff[c + 1];
  for (int i = s0; i < s1; ++i) {
    int s = tlist[i];
    acc = fmaf(tin[s * 128 + t], dinv[s] * dc, acc);
  }
  xa[t] = acc;
  __syncthreads();
  float th = 0.f;
#pragma unroll 4
  for (int k = 0; k < 128; ++k) th = fmaf(xa[k], gt[k * 128 + t], th);
  float vv = fmaxf(th + gcnb[t], 0.f);
  trow[t] = vv;
  __syncthreads();
  float qa = bq[t];
#pragma unroll 4
  for (int k = 0; k < 128; ++k) qa = fmaf(trow[k], Wqt[k * 128 + t], qa);
  qrow[t] = qa * 0.25f;  // 1/sqrt(DH)
  __syncthreads();
#pragma unroll
  for (int h = 0; h < 8; ++h) {
    float s = 0.f;
#pragma unroll
    for (int j = 0; j < 16; ++j) s = fmaf(Wk[(size_t)(h * 16 + j) * 128 + t], qrow[h * 16 + j], s);
    qk[((size_t)c * 8 + h) * 128 + t] = s;
  }
  if (t < 8) {
    float s = 0.f;
#pragma unroll
    for (int j = 0; j < 16; ++j) s = fmaf(qrow[t * 16 + j], bk[t * 16 + j], s);
    qb[c * 8 + t] = s;
  }
}

// ---------------- bu softmax partials: grid (C, SPL), bf16 gathers ----------------
__global__ __launch_bounds__(256) void hg_bu_part(
    const float* __restrict__ s_att, const unsigned short* __restrict__ hcell,
    const int* __restrict__ list, const int* __restrict__ coff,
    float* __restrict__ pm, float* __restrict__ pz, float* __restrict__ pmacc) {
  int c = blockIdx.x, sp = blockIdx.y, t = threadIdx.x;
  int s0 = coff[c], n = coff[c + 1] - s0;
  int chunk = (n + SPL - 1) / SPL;
  int b0 = min(n, sp * chunk), b1 = min(n, b0 + chunk);
  int cnt = b1 - b0;
  int tf = t & 127, half = t >> 7;
  __shared__ float red[32][8];
  __shared__ float mh[8];
  __shared__ int cells[64];
  __shared__ float wl[64][8];
  __shared__ float msh[8][128];
  int g = t >> 3, h8 = t & 7;
  float lm = -INFINITY;
  for (int i = g; i < cnt; i += 32) lm = fmaxf(lm, s_att[(size_t)list[s0 + b0 + i] * 8 + h8]);
  red[g][h8] = lm;
  __syncthreads();
  if (t < 8) {
    float m2 = -INFINITY;
#pragma unroll
    for (int i = 0; i < 32; ++i) m2 = fmaxf(m2, red[i][t]);
    mh[t] = m2;
  }
  __syncthreads();
  const float mloc = mh[t & 7];
  float zp = 0.f;
  float macc[8] = {0.f, 0.f, 0.f, 0.f, 0.f, 0.f, 0.f, 0.f};
  for (int cb = 0; cb < cnt; cb += 64) {
    int len = min(64, cnt - cb);
    if (t < len) cells[t] = list[s0 + b0 + cb + t];
    __syncthreads();
#pragma unroll
    for (int p = 0; p < 2; ++p) {
      int e = p * 32 + (t >> 3);
      if (e < len) {
        float w = __expf(s_att[(size_t)cells[e] * 8 + (t & 7)] - mloc);
        wl[e][t & 7] = w;
        zp += w;
      }
    }
    __syncthreads();
    for (int e = half; e < len; e += 2) {
      float x = b2f(hcell[(size_t)cells[e] * 128 + tf]);
      float4 w0 = *(const float4*)&wl[e][0];
      float4 w1 = *(const float4*)&wl[e][4];
      macc[0] = fmaf(w0.x, x, macc[0]);
      macc[1] = fmaf(w0.y, x, macc[1]);
      macc[2] = fmaf(w0.z, x, macc[2]);
      macc[3] = fmaf(w0.w, x, macc[3]);
      macc[4] = fmaf(w1.x, x, macc[4]);
      macc[5] = fmaf(w1.y, x, macc[5]);
      macc[6] = fmaf(w1.z, x, macc[6]);
      macc[7] = fmaf(w1.w, x, macc[7]);
    }
    __syncthreads();
  }
  red[t >> 3][t & 7] = zp;
  __syncthreads();
  int pidx = (c * SPL + sp) * 8;
  if (t < 8) {
    float z = 0.f;
#pragma unroll
    for (int i = 0; i < 32; ++i) z += red[i][t];
    pz[pidx + t] = z;
    pm[pidx + t] = mh[t];
  }
  if (half) {
#pragma unroll
    for (int h = 0; h < 8; ++h) msh[h][tf] = macc[h];
  }
  __syncthreads();
  if (!half) {
#pragma unroll
    for (int h = 0; h < 8; ++h) pmacc[(size_t)(pidx + h) * 128 + tf] = macc[h] + msh[h][tf];
  }
}

// ---------------- fused cluster chain: merge partials, Wv, Wo, td+GRU, gates, next GAT proj ----------------
__global__ __launch_bounds__(256) void hg_bu_chain(
    const float* __restrict__ pm, const float* __restrict__ pz, const float* __restrict__ pmacc,
    const float* __restrict__ Wv, const float* __restrict__ bv,
    const float* __restrict__ Wot, const float* __restrict__ bo,
    const float* __restrict__ Wcat_t, const float* __restrict__ bcat,
    const float* __restrict__ gatWt, const float* __restrict__ avs, const float* __restrict__ avd,
    float* __restrict__ tish, float* __restrict__ ccell,
    unsigned short* __restrict__ hprojc, float* __restrict__ a_s2, float* __restrict__ a_d2) {
  int c = blockIdx.x, t = threadIdx.x;
  int tf = t & 127, half = t >> 7;
  __shared__ float mh[8], zh[8];
  __shared__ float sscale[SPL][8];
  __shared__ float msh[8][128];
  __shared__ float b0[128], b1[128], part[2][128], catv[896];
  const int pbase = c * SPL * 8;
  if (t < 8) {
    float mg = -INFINITY;
#pragma unroll
    for (int s = 0; s < SPL; ++s) mg = fmaxf(mg, pm[pbase + s * 8 + t]);
    mh[t] = mg;
  }
  __syncthreads();
  if (t < SPL * 8) {
    int s = t >> 3, h = t & 7;
    float ms = pm[pbase + s * 8 + h];
    sscale[s][h] = (ms > -1e37f) ? __expf(ms - mh[h]) : 0.f;
  }
  __syncthreads();
  if (t < 8) {
    float z = 0.f;
#pragma unroll
    for (int s = 0; s < SPL; ++s) z += pz[pbase + s * 8 + t] * sscale[s][t];
    zh[t] = (z > 0.f) ? 1.f / z : 0.f;
  }
  __syncthreads();
#pragma unroll
  for (int hh = 0; hh < 4; ++hh) {
    int h = half * 4 + hh;
    float a = 0.f;
#pragma unroll
    for (int s = 0; s < SPL; ++s)
      a = fmaf(pmacc[(size_t)(pbase + s * 8 + h) * 128 + tf], sscale[s][h], a);
    msh[h][tf] = a * zh[h];
  }
  __syncthreads();
  {
    int h = tf >> 4;
    float ps = 0.f;
    const float* wp = Wv + (size_t)tf * 128 + half * 64;
    const float* mp = &msh[h][half * 64];
#pragma unroll 4
    for (int k = 0; k < 64; ++k) ps = fmaf(wp[k], mp[k], ps);
    part[half][tf] = ps;
  }
  __syncthreads();
  if (t < 128) b0[t] = part[0][t] + part[1][t] + bv[t];
  __syncthreads();
  int ks = half;
  {
    float ps = 0.f;
    const float* wp = Wot + (size_t)ks * 64 * 128 + tf;
#pragma unroll 4
    for (int k = 0; k < 64; ++k) ps = fmaf(b0[ks * 64 + k], wp[k * 128], ps);
    part[ks][tf] = ps;
  }
  __syncthreads();
  if (t < 128) {
    float vv = part[0][t] + part[1][t] + bo[t];
    b1[t] = vv;
    tish[c * 128 + t] = vv;
  }
  __syncthreads();
  for (int j = t; j < 896; j += 256) {
    float a = bcat[j];
#pragma unroll 4
    for (int k = 0; k < 128; ++k) a = fmaf(b1[k], Wcat_t[k * 896 + j], a);
    catv[j] = a;
  }
  __syncthreads();
  if (t < 128) {
    float td = catv[t];
    float r = 1.f / (1.f + expf(-(catv[128 + t] + catv[512 + t])));
    float zz = 1.f / (1.f + expf(-(catv[256 + t] + catv[640 + t])));
    float nn = tanhf(catv[384 + t] + r * catv[768 + t]);
    float cn = (1.f - zz) * nn + zz * td;
    ccell[c * 128 + t] = cn;
    b0[t] = cn;
  }
  __syncthreads();
  if (gatWt) {
    float ps = 0.f;
    const float* wp = gatWt + (size_t)ks * 64 * 128 + tf;
#pragma unroll 4
    for (int k = 0; k < 64; ++k) ps = fmaf(b0[ks * 64 + k], wp[k * 128], ps);
    part[ks][tf] = ps;
    __syncthreads();
    if (t < 128) {
      float hp = part[0][t] + part[1][t];
      hprojc[c * 128 + t] = f2b(hp);
      float pss = hp * avs[t], pdd = hp * avd[t];
      pss += __shfl_xor(pss, 1); pss += __shfl_xor(pss, 2); pss += __shfl_xor(pss, 4); pss += __shfl_xor(pss, 8);
      pdd += __shfl_xor(pdd, 1); pdd += __shfl_xor(pdd, 2); pdd += __shfl_xor(pdd, 4); pdd += __shfl_xor(pdd, 8);
      if ((t & 15) == 0) {
        a_s2[c * 8 + (t >> 4)] = pss;
        a_d2[c * 8 + (t >> 4)] = pdd;
      }
    }
  }
}

// ---------------- parallel dual-pool partials: grid PB blocks ----------------
__global__ __launch_bounds__(256) void hg_pool(const float* __restrict__ ccell2, const float* __restrict__ tish,
                                               const int* __restrict__ cnt, float* __restrict__ part) {
  int b = blockIdx.x, t = threadIdx.x;
  int c0 = b * (C / PB);
  if (t < 128) {
    float sm = 0.f, mx = -INFINITY;
#pragma unroll 4
    for (int i = 0; i < C / PB; ++i) {
      int c = c0 + i;
      float vv = ccell2[c * 128 + t];
      int n = cnt[c];
      sm += (float)n * vv;
      if (n > 0) mx = fmaxf(mx, vv);
    }
    part[b * 512 + t] = sm;
    part[b * 512 + 128 + t] = mx;
  } else {
    int tt = t - 128;
    float sm = 0.f, mx = -INFINITY;
#pragma unroll 4
    for (int i = 0; i < C / PB; ++i) {
      int c = c0 + i;
      float vv = tish[c * 128 + tt];
      sm += vv;
      mx = fmaxf(mx, vv);
    }
    part[b * 512 + 256 + tt] = sm;
    part[b * 512 + 384 + tt] = mx;
  }
}

// ---------------- classifier MLP (merges pool partials) ----------------
__global__ __launch_bounds__(256) void hg_mlp(const float* __restrict__ part, const float* __restrict__ Wc1t,
                                              const float* __restrict__ bc1, const float* __restrict__ Wc2t,
                                              const float* __restrict__ bc2, const float* __restrict__ Wc3,
                                              const float* __restrict__ bc3, float* __restrict__ outp) {
  __shared__ float emb[512], h1s[256], h2s[128];
  int t = threadIdx.x;
  if (t < 128) {
    float sm = 0.f, mx = -INFINITY;
#pragma unroll
    for (int b = 0; b < PB; ++b) {
      sm += part[b * 512 + t];
      mx = fmaxf(mx, part[b * 512 + 128 + t]);
    }
    emb[t] = sm / (float)N;
    emb[128 + t] = mx;
  } else {
    int tt = t - 128;
    float sm = 0.f, mx = -INFINITY;
#pragma unroll
    for (int b = 0; b < PB; ++b) {
      sm += part[b * 512 + 256 + tt];
      mx = fmaxf(mx, part[b * 512 + 384 + tt]);
    }
    emb[256 + tt] = sm * (1.f / (float)C);
    emb[384 + tt] = mx;
  }
  __syncthreads();
  float a = bc1[t];
#pragma unroll 4
  for (int kk = 0; kk < 512; ++kk) a = fmaf(emb[kk], Wc1t[kk * 256 + t], a);
  h1s[t] = fmaxf(a, 0.f);
  __syncthreads();
  if (t < 128) {
    float a2 = bc2[t];
#pragma unroll 4
    for (int kk = 0; kk < 256; ++kk) a2 = fmaf(h1s[kk], Wc2t[kk * 128 + t], a2);
    h2s[t] = fmaxf(a2, 0.f);
  }
  __syncthreads();
  if (t < 4) {
    float o = bc3[t];
    for (int kk = 0; kk < 128; ++kk) o = fmaf(h2s[kk], Wc3[t * 128 + kk], o);
    outp[t] = o;
  }
}

// ---------------- host launcher ----------------
extern "C" void kernel_launch(void* const* d_in, const int* in_sizes, int n_in,
                              void* d_out, int out_size, void* d_ws, size_t ws_size,
                              hipStream_t stream) {
  (void)in_sizes; (void)n_in; (void)out_size; (void)ws_size;
  const float* feat  = (const float*)d_in[0];
  const int*   eidx  = (const int*)d_in[1];
  const int*   lab   = (const int*)d_in[2];
  const int*   tidx  = (const int*)d_in[3];
  const float* Wcp   = (const float*)d_in[4];
  const float* bcp   = (const float*)d_in[5];
  const float* Wtp   = (const float*)d_in[6];
  const float* btp   = (const float*)d_in[7];
  const float* gatW  = (const float*)d_in[8];
  const float* gasrc = (const float*)d_in[9];
  const float* gadst = (const float*)d_in[10];
  const float* gatb  = (const float*)d_in[11];
  const float* gcnW  = (const float*)d_in[12];
  const float* gcnb  = (const float*)d_in[13];
  const float* buWq  = (const float*)d_in[14];
  const float* buWk  = (const float*)d_in[15];
  const float* buWv  = (const float*)d_in[16];
  const float* bubq  = (const float*)d_in[17];
  const float* bubk  = (const float*)d_in[18];
  const float* bubv  = (const float*)d_in[19];
  const float* buWo  = (const float*)d_in[20];
  const float* bubo  = (const float*)d_in[21];
  const float* tdWv  = (const float*)d_in[22];
  const float* tdbv  = (const float*)d_in[23];
  const float* tdWo  = (const float*)d_in[24];
  const float* tdbo  = (const float*)d_in[25];
  const float* Wih   = (const float*)d_in[26];
  const float* bih   = (const float*)d_in[27];
  const float* Whh   = (const float*)d_in[28];
  const float* bhh   = (const float*)d_in[29];
  const float* Wc1   = (const float*)d_in[30];
  const float* bc1   = (const float*)d_in[31];
  const float* Wc2   = (const float*)d_in[32];
  const float* bc2   = (const float*)d_in[33];
  const float* Wc3   = (const float*)d_in[34];
  const float* bc3   = (const float*)d_in[35];
  float* outp = (float*)d_out;

  const int* csrc = eidx;
  const int* cdst = eidx + E;
  const int* tsrc = tidx;
  const int* tdst = tidx + ET;

  char* w = (char*)d_ws;
  auto alloc = [&](size_t bytes) -> void* {
    void* p = (void*)w;
    w += (bytes + 255) & ~(size_t)255;
    return p;
  };
  char* cnt0 = w;
  int* deg_cell = (int*)alloc((size_t)N * 4);
  int* cur_cell = (int*)alloc((size_t)N * 4);
  int* clu_cnt  = (int*)alloc((size_t)C * 4);
  int* clu_cur  = (int*)alloc((size_t)C * 4);
  size_t cntBytes = (size_t)(w - cnt0);
  int* off_cell = (int*)alloc((size_t)(N + 1) * 4);
  int* btot     = (int*)alloc(64 * 4);
  int* csr      = (int*)alloc((size_t)E * 4);
  int* clu_off  = (int*)alloc((size_t)(C + 1) * 4);
  int* clu_list = (int*)alloc((size_t)N * 4);
  int* toff     = (int*)alloc((size_t)(C + 1) * 4);
  int* tlist    = (int*)alloc((size_t)ET * 4);
  float* dinv   = (float*)alloc((size_t)C * 4);
  unsigned short* buf1 = (unsigned short*)alloc((size_t)N * 128 * 2);  // bf16 cell_h
  unsigned short* buf2 = (unsigned short*)alloc((size_t)N * 128 * 2);  // bf16 hproj
  float* a_s    = (float*)alloc((size_t)N * 8 * 4);
  float* a_d    = (float*)alloc((size_t)N * 8 * 4);
  float* s_att  = (float*)alloc((size_t)N * 8 * 4);
  float* tish   = (float*)alloc((size_t)C * 128 * 4);
  float* qkb    = (float*)alloc((size_t)C * 8 * 128 * 4);
  float* qbb    = (float*)alloc((size_t)C * 8 * 4);
  float* ccell  = (float*)alloc((size_t)C * 128 * 4);
  unsigned short* hprojc = (unsigned short*)alloc((size_t)C * 128 * 2);
  float* a_sc   = (float*)alloc((size_t)C * 8 * 4);
  float* a_dc   = (float*)alloc((size_t)C * 8 * 4);
  float* Ttab   = (float*)alloc((size_t)C * 256 * 8 * 4);  // 2 MB pairwise weights
  float* pm     = (float*)alloc((size_t)C * SPL * 8 * 4);
  float* pz     = (float*)alloc((size_t)C * SPL * 8 * 4);
  float* pmacc  = (float*)alloc((size_t)C * SPL * 8 * 128 * 4);
  float* poolp  = (float*)alloc((size_t)PB * 512 * 4);
  float* A_td   = (float*)alloc(128 * 128 * 4);
  float* Wcat_t = (float*)alloc(128 * 896 * 4);
  float* bcat   = (float*)alloc(896 * 4);
  short* Wcompb = (short*)alloc(144 * 256 * 2);   // bf16 composite weight + coef cols
  float* bcomp  = (float*)alloc(128 * 4);
  float* sbias  = (float*)alloc(16 * 4);
  float* Wtpt   = (float*)alloc(256 * 128 * 4);
  float* g1t    = (float*)alloc(128 * 128 * 4);
  float* g2t    = (float*)alloc(128 * 128 * 4);
  float* Wqt    = (float*)alloc(128 * 128 * 4);
  float* Wot    = (float*)alloc(128 * 128 * 4);
  float* gatW2t = (float*)alloc(128 * 128 * 4);
  float* Wc1t   = (float*)alloc(512 * 256 * 4);
  float* Wc2t   = (float*)alloc(256 * 128 * 4);

  hipMemsetAsync(cnt0, 0, cntBytes, stream);

  hg_hist<<<(E + 255) / 256, 256, 0, stream>>>(cdst, deg_cell, lab, clu_cnt);
  hg_scan1<<<NB, 256, 0, stream>>>(deg_cell, off_cell, btot, N);
  hg_scan2_setup<<<3, 256, 0, stream>>>(btot, off_cell, clu_cnt, clu_off, tsrc, tdst, toff, tlist, dinv);
  hg_scan3<<<NB, 256, 0, stream>>>(off_cell, btot, N);
  hg_scatter<<<(E + 255) / 256, 256, 0, stream>>>(csrc, cdst, off_cell, cur_cell, csr,
                                                  lab, clu_off, clu_cur, clu_list);

  PrepArgs pa;
  pa.j[0] = {Wtp,            Wtpt,   128, 256, 128};
  pa.j[1] = {gcnW,           g1t,    128, 128, 128};
  pa.j[2] = {gcnW + 128*128, g2t,    128, 128, 128};
  pa.j[3] = {buWq,           Wqt,    128, 128, 128};
  pa.j[4] = {buWo,           Wot,    128, 128, 128};
  pa.j[5] = {gatW + 128*128, gatW2t, 128, 128, 128};
  pa.j[6] = {Wc1,            Wc1t,   256, 512, 256};
  pa.j[7] = {Wc2,            Wc2t,   128, 256, 128};
  pa.gatW1 = gatW; pa.Wcp = Wcp; pa.bcp = bcp; pa.Wcompb = Wcompb; pa.bcomp = bcomp;
  pa.tdWo = tdWo; pa.tdWv = tdWv; pa.tdbv = tdbv; pa.tdbo = tdbo;
  pa.A_td = A_td; pa.Wcat_t = Wcat_t; pa.bcat = bcat;
  pa.avs = gasrc; pa.avd = gadst; pa.sbias = sbias;
  hg_prep1<<<dim3(128, 11), 256, 0, stream>>>(pa);
  hg_pc2b<<<384, 256, 0, stream>>>(Wih, bih, Whh, bhh, A_td, Wcat_t, bcat);

  const int RT = (N + 63) / 64;  // 938 row tiles (64 rows each)
  hg_gemm_coef<<<RT + C, 256, 0, stream>>>(feat, N, RT, Wcompb, bcomp, sbias, buf2, a_s, a_d,
                                           clu_list, clu_off, Wtpt, btp, tish);
  // ---- layer 1 ----
  hg_gcn_q<<<C, 128, 0, stream>>>(tish, toff, tlist, dinv, g1t, gcnb, Wqt, bubq, buWk, bubk, qkb, qbb);
  hg_gat_agg<<<(N + 3) / 4, 256, 0, stream>>>(buf2, a_s, a_d, off_cell, csr, gatb, buf1,
                                              qkb, qbb, lab, clu_list, s_att, N);
  hg_bu_part<<<dim3(C, SPL), 256, 0, stream>>>(s_att, buf1, clu_list, clu_off, pm, pz, pmacc);
  hg_bu_chain<<<C, 256, 0, stream>>>(pm, pz, pmacc, buWv, bubv, Wot, bubo, Wcat_t, bcat,
                                     gatW2t, gasrc + 128, gadst + 128, tish, ccell, hprojc, a_sc, a_dc);
  // ---- layer 2 ----
  hg_gcn_q<<<C, 128, 0, stream>>>(tish, toff, tlist, dinv, g2t, gcnb + 128, Wqt, bubq, buWk, bubk, qkb, qbb);
  hg_ttab<<<C, 256, 0, stream>>>(a_sc, a_dc, Ttab);
  hg_gat_agg2<<<(N + 3) / 4, 256, 0, stream>>>(hprojc, Ttab, lab, off_cell, csr, gatb + 128, buf1,
                                               qkb, qbb, clu_list, s_att, N);
  hg_bu_part<<<dim3(C, SPL), 256, 0, stream>>>(s_att, buf1, clu_list, clu_off, pm, pz, pmacc);
  hg_bu_chain<<<C, 256, 0, stream>>>(pm, pz, pmacc, buWv, bubv, Wot, bubo, Wcat_t, bcat,
                                     nullptr, nullptr, nullptr, tish, ccell, nullptr, nullptr, nullptr);

  hg_pool<<<PB, 256, 0, stream>>>(ccell, tish, clu_cnt, poolp);
  hg_mlp<<<1, 256, 0, stream>>>(poolp, Wc1t, bc1, Wc2t, bc2, Wc3, bc3, outp);
}

// Round 13
// 546.664 us; speedup vs baseline: 1.0624x; 1.0624x over previous
//
#include <hip/hip_runtime.h>
#include <math.h>

constexpr int N  = 60000;
constexpr int F  = 256;
constexpr int H  = 128;
constexpr int C  = 256;
constexpr int E  = 600000;
constexpr int ET = 1500;
constexpr int NB = (N + 1023) / 1024;  // 59 scan blocks
constexpr int SPL = 8;                 // bu softmax splits per cluster
constexpr int PB  = 16;                // pooling blocks

typedef __attribute__((ext_vector_type(8))) short short8;
typedef __attribute__((ext_vector_type(4))) float f32x4;

__device__ __forceinline__ unsigned short f2b(float f) {  // fp32 -> bf16 (RNE)
  unsigned int u = __float_as_uint(f);
  return (unsigned short)((u + 0x7FFFu + ((u >> 16) & 1u)) >> 16);
}
__device__ __forceinline__ float b2f(unsigned short b) {
  return __uint_as_float(((unsigned int)b) << 16);
}

// ---------------- histograms (cell-dst degree + cluster counts) ----------------
__global__ void hg_hist(const int* __restrict__ cdst, int* __restrict__ deg,
                        const int* __restrict__ lab, int* __restrict__ ccnt) {
  int e = blockIdx.x * 256 + threadIdx.x;
  if (e < E) atomicAdd(&deg[cdst[e]], 1);
  if (e < N) atomicAdd(&ccnt[lab[e]], 1);
}

// ---------------- multi-block scan ----------------
__global__ __launch_bounds__(256) void hg_scan1(const int* __restrict__ deg, int* __restrict__ off,
                                                int* __restrict__ btot, int n) {
  int b = blockIdx.x, t = threadIdx.x;
  int i0 = b * 1024 + t * 4;
  __shared__ int sums[256];
  int d0 = 0, d1 = 0, d2 = 0, d3 = 0;
  if (i0 + 3 < n) {
    int4 dd = *(const int4*)&deg[i0];
    d0 = dd.x; d1 = dd.y; d2 = dd.z; d3 = dd.w;
  } else {
    if (i0     < n) d0 = deg[i0];
    if (i0 + 1 < n) d1 = deg[i0 + 1];
    if (i0 + 2 < n) d2 = deg[i0 + 2];
    if (i0 + 3 < n) d3 = deg[i0 + 3];
  }
  int s = d0 + d1 + d2 + d3;
  sums[t] = s;
  __syncthreads();
  for (int ofs = 1; ofs < 256; ofs <<= 1) {
    int v = (t >= ofs) ? sums[t - ofs] : 0;
    __syncthreads();
    sums[t] += v;
    __syncthreads();
  }
  int excl = sums[t] - s;
  if (t == 255) btot[b] = sums[t];
  int run = excl;
  if (i0     < n) off[i0]     = run; run += d0;
  if (i0 + 1 < n) off[i0 + 1] = run; run += d1;
  if (i0 + 2 < n) off[i0 + 2] = run; run += d2;
  if (i0 + 3 < n) off[i0 + 3] = run;
}

// block0: scan of btot; block1: cluster-count scan; block2: tissue CSR + dinv
__global__ __launch_bounds__(256) void hg_scan2_setup(int* __restrict__ btot, int* __restrict__ off,
                                                      const int* __restrict__ ccnt, int* __restrict__ coff,
                                                      const int* __restrict__ tsrc, const int* __restrict__ tdst,
                                                      int* __restrict__ toff, int* __restrict__ tlist,
                                                      float* __restrict__ dinv) {
  __shared__ int sa[256], sb[256], sc2[256];
  int t = threadIdx.x;
  if (blockIdx.x == 0) {
    if (t < 64) sa[t] = (t < NB) ? btot[t] : 0;
    __syncthreads();
    if (t == 0) {
      int r = 0;
      for (int i = 0; i < NB; ++i) { int v = sa[i]; sa[i] = r; r += v; }
      off[N] = r;
    }
    __syncthreads();
    if (t < NB) btot[t] = sa[t];
  } else if (blockIdx.x == 1) {
    int v0 = ccnt[t];
    sa[t] = v0;
    __syncthreads();
    for (int ofs = 1; ofs < 256; ofs <<= 1) {
      int v = (t >= ofs) ? sa[t - ofs] : 0;
      __syncthreads();
      sa[t] += v;
      __syncthreads();
    }
    coff[t + 1] = sa[t];
    if (t == 0) coff[0] = 0;
  } else {
    sa[t] = 0;
    __syncthreads();
    for (int e = t; e < ET; e += 256) atomicAdd(&sa[tdst[e]], 1);
    __syncthreads();
    int v = sa[t];
    dinv[t] = rsqrtf((float)(v + 1));
    sb[t] = v;
    __syncthreads();
    for (int ofs = 1; ofs < 256; ofs <<= 1) {
      int u = (t >= ofs) ? sb[t - ofs] : 0;
      __syncthreads();
      sb[t] += u;
      __syncthreads();
    }
    toff[t + 1] = sb[t];
    if (t == 0) toff[0] = 0;
    sc2[t] = sb[t] - v;
    __syncthreads();
    for (int e = t; e < ET; e += 256) {
      int d = tdst[e];
      int p = atomicAdd(&sc2[d], 1);
      tlist[p] = tsrc[e];
    }
  }
}

__global__ void hg_scan3(int* __restrict__ off, const int* __restrict__ btot, int n) {
  int b = blockIdx.x;
  int addv = btot[b];
  int i0 = b * 1024 + threadIdx.x * 4;
#pragma unroll
  for (int r = 0; r < 4; ++r)
    if (i0 + r < n) off[i0 + r] += addv;
}

// merged: cell-edge CSR scatter + cluster-list scatter
__global__ void hg_scatter(const int* __restrict__ csrc, const int* __restrict__ cdst,
                           const int* __restrict__ off, int* __restrict__ cur, int* __restrict__ csr,
                           const int* __restrict__ lab, const int* __restrict__ coff,
                           int* __restrict__ ccur, int* __restrict__ list) {
  int e = blockIdx.x * 256 + threadIdx.x;
  if (e < E) {
    int d = cdst[e];
    int p = atomicAdd(&cur[d], 1);
    csr[off[d] + p] = csrc[e];
  }
  if (e < N) {
    int c = lab[e];
    int p = atomicAdd(&ccur[c], 1);
    list[coff[c] + p] = e;
  }
}

// ---------------- prep: 8 transposes + pc0(bf16) + pc1 (grid y = job) ----------------
struct TJob { const float* src; float* dst; int SR; int SC; int dld; };
struct PrepArgs {
  TJob j[8];
  const float* gatW1; const float* Wcp; const float* bcp; short* Wcompb; float* bcomp;
  const float* tdWo; const float* tdWv; const float* tdbv; const float* tdbo;
  float* A_td; float* Wcat_t; float* bcat;
};

__global__ __launch_bounds__(256) void hg_prep1(PrepArgs a) {
  int y = blockIdx.y, t = threadIdx.x;
  if (y < 8) {
    TJob jb = a.j[y];
    int total = jb.SR * jb.SC;
    for (int idx = blockIdx.x * 256 + t; idx < total; idx += gridDim.x * 256) {
      int r = idx / jb.SC, c = idx - r * jb.SC;
      jb.dst[(size_t)c * jb.dld + r] = jb.src[idx];
    }
  } else if (y == 8) {
    // pc0: Wcomp[j][k] = sum_m gatW1[j][m]*Wcp[m][k]  (bf16, j-major for MFMA B frags)
    int j = blockIdx.x, k = t;
    float acc = 0.f;
#pragma unroll 4
    for (int m = 0; m < 128; ++m) acc = fmaf(a.gatW1[j * 128 + m], a.Wcp[m * 256 + k], acc);
    a.Wcompb[(size_t)j * 256 + k] = (short)f2b(acc);
    if (k == 0) {
      float b = 0.f;
      for (int m = 0; m < 128; ++m) b = fmaf(a.gatW1[j * 128 + m], a.bcp[m], b);
      a.bcomp[j] = b;
    }
  } else if (blockIdx.x < 64) {
    int j = blockIdx.x * 2 + (t >> 7), k = t & 127;
    float acc = 0.f;
#pragma unroll 4
    for (int p = 0; p < 128; ++p) acc = fmaf(a.tdWo[j * 128 + p], a.tdWv[p * 128 + k], acc);
    a.A_td[j * 128 + k] = acc;
    a.Wcat_t[k * 896 + j] = acc;
    if (k == 0) {
      float b = 0.f;
      for (int p = 0; p < 128; ++p) b = fmaf(a.tdWo[j * 128 + p], a.tdbv[p], b);
      a.bcat[j] = b + a.tdbo[j];
    }
  }
}

__global__ __launch_bounds__(256) void hg_pc2b(const float* __restrict__ Wih, const float* __restrict__ bih,
                                               const float* __restrict__ Whh, const float* __restrict__ bhh,
                                               const float* __restrict__ A_td, float* __restrict__ Wcat_t,
                                               float* __restrict__ bcat) {
  int jj = blockIdx.x * 2 + (threadIdx.x >> 7), k = threadIdx.x & 127;
  const float* coef;
  float extra, bb;
  int dcol, j;
  if (jj < 384) {
    j = jj; coef = Wih + (size_t)j * 256; extra = Wih[(size_t)j * 256 + 128 + k]; dcol = 128 + j; bb = bih[j];
  } else {
    j = jj - 384; coef = Whh + (size_t)j * 128; extra = 0.f; dcol = 512 + j; bb = bhh[j];
  }
  float a = 0.f;
#pragma unroll 4
  for (int m = 0; m < 128; ++m) a = fmaf(coef[m], A_td[m * 128 + k], a);
  Wcat_t[k * 896 + dcol] = a + extra;
  if (k == 0) {
    float b = 0.f;
    for (int m = 0; m < 128; ++m) b = fmaf(coef[m], bcat[m], b);
    bcat[dcol] = b + bb;
  }
}

// ---------------- MFMA bf16 GEMM (K=256, tile 128x128, no LDS) + GAT-coef epilogue ----------------
__global__ __launch_bounds__(256, 3) void hg_gemm_coef(
    const float* __restrict__ A, int M, int rtiles,
    const short* __restrict__ Wb,          // bf16 [128][256] j-major
    const float* __restrict__ bias,
    unsigned short* __restrict__ outp,     // bf16 [M][128]
    const float* __restrict__ avs, const float* __restrict__ avd,
    float* __restrict__ o_s, float* __restrict__ o_d,
    const int* __restrict__ list, const int* __restrict__ coff,
    const float* __restrict__ Wtpt, const float* __restrict__ btp, float* __restrict__ tish) {
  __shared__ float mrow[256];
  const int t = threadIdx.x;

  if (blockIdx.x >= rtiles) {
    // ---- tissue init: per-cluster mean + projection (fp32) ----
    int c = blockIdx.x - rtiles;
    int s0 = coff[c], n = coff[c + 1] - s0;
    float acc = 0.f;
#pragma unroll 4
    for (int i = 0; i < n; ++i) acc += A[(size_t)list[s0 + i] * F + t];
    mrow[t] = acc / fmaxf((float)n, 1.f);
    __syncthreads();
    if (t < 128) {
      float a = btp[t];
#pragma unroll 4
      for (int k = 0; k < 256; ++k) a = fmaf(mrow[k], Wtpt[k * 128 + t], a);
      tish[c * 128 + t] = a;
    }
    return;
  }

  const int w = t >> 6, l = t & 63;
  const int li = l & 15, lk = l >> 4;   // li: row/col within 16-tile, lk: k-group
  const int m0 = blockIdx.x * 128 + w * 32;

  f32x4 zero = {0.f, 0.f, 0.f, 0.f};
  f32x4 acc[2][8];
#pragma unroll
  for (int rt = 0; rt < 2; ++rt)
#pragma unroll
    for (int ct = 0; ct < 8; ++ct) acc[rt][ct] = zero;

  const int r0 = m0 + li, r1 = m0 + 16 + li;
  const bool v0 = r0 < M, v1 = r1 < M;
  const float* a0p = A + (size_t)r0 * 256 + lk * 8;
  const float* a1p = A + (size_t)r1 * 256 + lk * 8;

  for (int kc = 0; kc < 256; kc += 32) {
    short8 bf[8];
#pragma unroll
    for (int ct = 0; ct < 8; ++ct)
      bf[ct] = *(const short8*)&Wb[(size_t)(ct * 16 + li) * 256 + kc + lk * 8];
    short8 af0 = {0, 0, 0, 0, 0, 0, 0, 0};
    short8 af1 = {0, 0, 0, 0, 0, 0, 0, 0};
    if (v0) {
      float4 x = *(const float4*)(a0p + kc);
      float4 y = *(const float4*)(a0p + kc + 4);
      af0[0] = (short)f2b(x.x); af0[1] = (short)f2b(x.y); af0[2] = (short)f2b(x.z); af0[3] = (short)f2b(x.w);
      af0[4] = (short)f2b(y.x); af0[5] = (short)f2b(y.y); af0[6] = (short)f2b(y.z); af0[7] = (short)f2b(y.w);
    }
    if (v1) {
      float4 x = *(const float4*)(a1p + kc);
      float4 y = *(const float4*)(a1p + kc + 4);
      af1[0] = (short)f2b(x.x); af1[1] = (short)f2b(x.y); af1[2] = (short)f2b(x.z); af1[3] = (short)f2b(x.w);
      af1[4] = (short)f2b(y.x); af1[5] = (short)f2b(y.y); af1[6] = (short)f2b(y.z); af1[7] = (short)f2b(y.w);
    }
#pragma unroll
    for (int ct = 0; ct < 8; ++ct) {
      acc[0][ct] = __builtin_amdgcn_mfma_f32_16x16x32_bf16(af0, bf[ct], acc[0][ct], 0, 0, 0);
      acc[1][ct] = __builtin_amdgcn_mfma_f32_16x16x32_bf16(af1, bf[ct], acc[1][ct], 0, 0, 0);
    }
  }

  // epilogue: bias, bf16 store, per-head coef dots (o_s/o_d)
#pragma unroll
  for (int ct = 0; ct < 8; ++ct) {
    float bj = bias[ct * 16 + li];
    float as = avs[ct * 16 + li];
    float ad = avd[ct * 16 + li];
#pragma unroll
    for (int rt = 0; rt < 2; ++rt) {
#pragma unroll
      for (int r = 0; r < 4; ++r) {
        int gm = m0 + rt * 16 + lk * 4 + r;
        float v = acc[rt][ct][r] + bj;
        if (gm < M) outp[(size_t)gm * 128 + ct * 16 + li] = f2b(v);
        float ps = v * as, pd = v * ad;
        ps += __shfl_xor(ps, 1); ps += __shfl_xor(ps, 2); ps += __shfl_xor(ps, 4); ps += __shfl_xor(ps, 8);
        pd += __shfl_xor(pd, 1); pd += __shfl_xor(pd, 2); pd += __shfl_xor(pd, 4); pd += __shfl_xor(pd, 8);
        if (li == 0 && gm < M) {
          o_s[(size_t)gm * 8 + ct] = ps;
          o_d[(size_t)gm * 8 + ct] = pd;
        }
      }
    }
  }
}

// ---------------- GAT aggregation: one WAVE per node, bf16 gathers ----------------
#define GMAXE 64
__global__ __launch_bounds__(256) void hg_gat_agg(
    const unsigned short* __restrict__ hproj, const float* __restrict__ a_s,
    const float* __restrict__ a_d, const int* __restrict__ remap,
    const int* __restrict__ off, const int* __restrict__ csr,
    const float* __restrict__ bias, unsigned short* __restrict__ outh,
    const float* __restrict__ qk, const float* __restrict__ qb,
    const int* __restrict__ lab, const int* __restrict__ nodelist,
    float* __restrict__ satt, int nNodes) {
  const int wid = threadIdx.x >> 6;
  const int l = threadIdx.x & 63;
  const int gid = blockIdx.x * 4 + wid;
  __shared__ int srcs_s[4][GMAXE];
  __shared__ float w_s[4][GMAXE][8];
  if (gid >= nNodes) return;
  const int node = nodelist[gid];
  int* srcs = srcs_s[wid];
  float (*wls)[8] = w_s[wid];
  const int o0 = off[node], deg = off[node + 1] - o0;
  const int cl = lab[node];
  const int dl = remap ? cl : node;
  const int hsc = l & 7;
  const int q4 = l & 31;
  const int sub = l >> 5;
  const int hq = q4 >> 2;
  const float adh = a_d[dl * 8 + hsc];
  const float ash = a_s[dl * 8 + hsc];
  float msc = -INFINITY, zsc = 0.f;
  float4 acc = make_float4(0.f, 0.f, 0.f, 0.f);
  const ushort4* hp4 = (const ushort4*)hproj;  // 4 bf16 per element

  for (int cb = 0; cb < deg; cb += GMAXE) {
    const int len = min(GMAXE, deg - cb);
    if (l < len) {
      int s = csr[o0 + cb + l];
      srcs[l] = remap ? remap[s] : s;
    }
    asm volatile("s_waitcnt lgkmcnt(0)" ::: "memory");
    float lm = -INFINITY;
    for (int base = 0; base < len; base += 8) {
      int e = base + (l >> 3);
      if (e < len) {
        float sc = a_s[srcs[e] * 8 + hsc] + adh;
        sc = sc > 0.f ? sc : 0.2f * sc;
        wls[e][hsc] = sc;
        lm = fmaxf(lm, sc);
      }
    }
    lm = fmaxf(lm, __shfl_xor(lm, 8));
    lm = fmaxf(lm, __shfl_xor(lm, 16));
    lm = fmaxf(lm, __shfl_xor(lm, 32));
    float mnew = fmaxf(msc, lm);
    float rs = __expf(msc - mnew);
    float zc = 0.f;
    asm volatile("s_waitcnt lgkmcnt(0)" ::: "memory");
    for (int base = 0; base < len; base += 8) {
      int e = base + (l >> 3);
      if (e < len) {
        float wv = __expf(wls[e][hsc] - mnew);
        wls[e][hsc] = wv;
        zc += wv;
      }
    }
    asm volatile("s_waitcnt lgkmcnt(0)" ::: "memory");
    zc += __shfl_xor(zc, 8); zc += __shfl_xor(zc, 16); zc += __shfl_xor(zc, 32);
    zsc = zsc * rs + zc;
    msc = mnew;
    float rsa = __shfl(rs, hq);
    acc.x *= rsa; acc.y *= rsa; acc.z *= rsa; acc.w *= rsa;
    for (int e = sub; e < len; e += 2) {
      float wv = wls[e][hq];
      ushort4 hv = hp4[(size_t)srcs[e] * 32 + q4];
      acc.x = fmaf(wv, b2f(hv.x), acc.x);
      acc.y = fmaf(wv, b2f(hv.y), acc.y);
      acc.z = fmaf(wv, b2f(hv.z), acc.z);
      acc.w = fmaf(wv, b2f(hv.w), acc.w);
    }
  }
  float ssl = ash + adh;
  ssl = ssl > 0.f ? ssl : 0.2f * ssl;
  float mnew = fmaxf(msc, ssl);
  float rs = __expf(msc - mnew);
  float wsl = __expf(ssl - mnew);
  zsc = zsc * rs + wsl;
  float rsa = __shfl(rs, hq);
  float wsa = __shfl(wsl, hq);
  float zh = __shfl(zsc, hq);
  acc.x *= rsa; acc.y *= rsa; acc.z *= rsa; acc.w *= rsa;
  acc.x += __shfl_xor(acc.x, 32);
  acc.y += __shfl_xor(acc.y, 32);
  acc.z += __shfl_xor(acc.z, 32);
  acc.w += __shfl_xor(acc.w, 32);
  ushort4 hvs = hp4[(size_t)dl * 32 + q4];
  acc.x = fmaf(wsa, b2f(hvs.x), acc.x);
  acc.y = fmaf(wsa, b2f(hvs.y), acc.y);
  acc.z = fmaf(wsa, b2f(hvs.z), acc.z);
  acc.w = fmaf(wsa, b2f(hvs.w), acc.w);
  float inv = 1.f / zh;
  float4 bv4 = *(const float4*)&bias[q4 * 4];
  float4 o;
  o.x = acc.x * inv + bv4.x;
  o.y = acc.y * inv + bv4.y;
  o.z = acc.z * inv + bv4.z;
  o.w = acc.w * inv + bv4.w;
  o.x = o.x > 0.f ? o.x : __expf(o.x) - 1.f;
  o.y = o.y > 0.f ? o.y : __expf(o.y) - 1.f;
  o.z = o.z > 0.f ? o.z : __expf(o.z) - 1.f;
  o.w = o.w > 0.f ? o.w : __expf(o.w) - 1.f;
  if (sub == 0) {
    ushort4 ov = make_ushort4(f2b(o.x), f2b(o.y), f2b(o.z), f2b(o.w));
    ((ushort4*)outh)[(size_t)node * 32 + q4] = ov;
  }

  // s_att epilogue (qk L2-hot via clu_list ordering)
  const float4* qk4 = (const float4*)(qk + (size_t)cl * 1024);
  float p0, p1, p2, p3;
  {
    float4 qv0 = qk4[(sub * 4 + 0) * 32 + q4];
    float4 qv1 = qk4[(sub * 4 + 1) * 32 + q4];
    float4 qv2 = qk4[(sub * 4 + 2) * 32 + q4];
    float4 qv3 = qk4[(sub * 4 + 3) * 32 + q4];
    p0 = o.x * qv0.x + o.y * qv0.y + o.z * qv0.z + o.w * qv0.w;
    p1 = o.x * qv1.x + o.y * qv1.y + o.z * qv1.z + o.w * qv1.w;
    p2 = o.x * qv2.x + o.y * qv2.y + o.z * qv2.z + o.w * qv2.w;
    p3 = o.x * qv3.x + o.y * qv3.y + o.z * qv3.z + o.w * qv3.w;
  }
  int b4f = (l >> 4) & 1, b3f = (l >> 3) & 1;
  float snd0 = b4f ? p0 : p2, snd1 = b4f ? p1 : p3;
  float kp0  = b4f ? p2 : p0, kp1  = b4f ? p3 : p1;
  kp0 += __shfl_xor(snd0, 16);
  kp1 += __shfl_xor(snd1, 16);
  float snd = b3f ? kp0 : kp1;
  float kp  = b3f ? kp1 : kp0;
  kp += __shfl_xor(snd, 8);
  kp += __shfl_xor(kp, 4);
  kp += __shfl_xor(kp, 2);
  kp += __shfl_xor(kp, 1);
  int h = sub * 4 + b4f * 2 + b3f;
  if ((l & 7) == 0) satt[(size_t)node * 8 + h] = kp + qb[cl * 8 + h];
}

// ---------------- tissue GCN + q projection + qk/qb tables ----------------
__global__ __launch_bounds__(128) void hg_gcn_q(const float* __restrict__ tin, const int* __restrict__ toff,
                                                const int* __restrict__ tlist, const float* __restrict__ dinv,
                                                const float* __restrict__ gt, const float* __restrict__ gcnb,
                                                const float* __restrict__ Wqt, const float* __restrict__ bq,
                                                const float* __restrict__ Wk, const float* __restrict__ bk,
                                                float* __restrict__ qk, float* __restrict__ qb) {
  int c = blockIdx.x, t = threadIdx.x;
  __shared__ float xa[128], trow[128], qrow[128];
  float dc = dinv[c];
  float acc = tin[c * 128 + t] * dc * dc;
  int s0 = toff[c], s1 = toff[c + 1];
  for (int i = s0; i < s1; ++i) {
    int s = tlist[i];
    acc = fmaf(tin[s * 128 + t], dinv[s] * dc, acc);
  }
  xa[t] = acc;
  __syncthreads();
  float th = 0.f;
#pragma unroll 4
  for (int k = 0; k < 128; ++k) th = fmaf(xa[k], gt[k * 128 + t], th);
  float vv = fmaxf(th + gcnb[t], 0.f);
  trow[t] = vv;
  __syncthreads();
  float qa = bq[t];
#pragma unroll 4
  for (int k = 0; k < 128; ++k) qa = fmaf(trow[k], Wqt[k * 128 + t], qa);
  qrow[t] = qa * 0.25f;  // 1/sqrt(DH)
  __syncthreads();
#pragma unroll
  for (int h = 0; h < 8; ++h) {
    float s = 0.f;
#pragma unroll
    for (int j = 0; j < 16; ++j) s = fmaf(Wk[(size_t)(h * 16 + j) * 128 + t], qrow[h * 16 + j], s);
    qk[((size_t)c * 8 + h) * 128 + t] = s;
  }
  if (t < 8) {
    float s = 0.f;
#pragma unroll
    for (int j = 0; j < 16; ++j) s = fmaf(qrow[t * 16 + j], bk[t * 16 + j], s);
    qb[c * 8 + t] = s;
  }
}

// ---------------- bu softmax partials: grid (C, SPL), bf16 gathers ----------------
__global__ __launch_bounds__(256) void hg_bu_part(
    const float* __restrict__ s_att, const unsigned short* __restrict__ hcell,
    const int* __restrict__ list, const int* __restrict__ coff,
    float* __restrict__ pm, float* __restrict__ pz, float* __restrict__ pmacc) {
  int c = blockIdx.x, sp = blockIdx.y, t = threadIdx.x;
  int s0 = coff[c], n = coff[c + 1] - s0;
  int chunk = (n + SPL - 1) / SPL;
  int b0 = min(n, sp * chunk), b1 = min(n, b0 + chunk);
  int cnt = b1 - b0;
  int tf = t & 127, half = t >> 7;
  __shared__ float red[32][8];
  __shared__ float mh[8];
  __shared__ int cells[64];
  __shared__ float wl[64][8];
  __shared__ float msh[8][128];
  int g = t >> 3, h8 = t & 7;
  float lm = -INFINITY;
  for (int i = g; i < cnt; i += 32) lm = fmaxf(lm, s_att[(size_t)list[s0 + b0 + i] * 8 + h8]);
  red[g][h8] = lm;
  __syncthreads();
  if (t < 8) {
    float m2 = -INFINITY;
#pragma unroll
    for (int i = 0; i < 32; ++i) m2 = fmaxf(m2, red[i][t]);
    mh[t] = m2;
  }
  __syncthreads();
  const float mloc = mh[t & 7];
  float zp = 0.f;
  float macc[8] = {0.f, 0.f, 0.f, 0.f, 0.f, 0.f, 0.f, 0.f};
  for (int cb = 0; cb < cnt; cb += 64) {
    int len = min(64, cnt - cb);
    if (t < len) cells[t] = list[s0 + b0 + cb + t];
    __syncthreads();
#pragma unroll
    for (int p = 0; p < 2; ++p) {
      int e = p * 32 + (t >> 3);
      if (e < len) {
        float w = __expf(s_att[(size_t)cells[e] * 8 + (t & 7)] - mloc);
        wl[e][t & 7] = w;
        zp += w;
      }
    }
    __syncthreads();
    for (int e = half; e < len; e += 2) {
      float x = b2f(hcell[(size_t)cells[e] * 128 + tf]);
      float4 w0 = *(const float4*)&wl[e][0];
      float4 w1 = *(const float4*)&wl[e][4];
      macc[0] = fmaf(w0.x, x, macc[0]);
      macc[1] = fmaf(w0.y, x, macc[1]);
      macc[2] = fmaf(w0.z, x, macc[2]);
      macc[3] = fmaf(w0.w, x, macc[3]);
      macc[4] = fmaf(w1.x, x, macc[4]);
      macc[5] = fmaf(w1.y, x, macc[5]);
      macc[6] = fmaf(w1.z, x, macc[6]);
      macc[7] = fmaf(w1.w, x, macc[7]);
    }
    __syncthreads();
  }
  red[t >> 3][t & 7] = zp;
  __syncthreads();
  int pidx = (c * SPL + sp) * 8;
  if (t < 8) {
    float z = 0.f;
#pragma unroll
    for (int i = 0; i < 32; ++i) z += red[i][t];
    pz[pidx + t] = z;
    pm[pidx + t] = mh[t];
  }
  if (half) {
#pragma unroll
    for (int h = 0; h < 8; ++h) msh[h][tf] = macc[h];
  }
  __syncthreads();
  if (!half) {
#pragma unroll
    for (int h = 0; h < 8; ++h) pmacc[(size_t)(pidx + h) * 128 + tf] = macc[h] + msh[h][tf];
  }
}

// ---------------- fused cluster chain: merge partials, Wv, Wo, td+GRU, gates, next GAT proj ----------------
__global__ __launch_bounds__(256) void hg_bu_chain(
    const float* __restrict__ pm, const float* __restrict__ pz, const float* __restrict__ pmacc,
    const float* __restrict__ Wv, const float* __restrict__ bv,
    const float* __restrict__ Wot, const float* __restrict__ bo,
    const float* __restrict__ Wcat_t, const float* __restrict__ bcat,
    const float* __restrict__ gatWt, const float* __restrict__ avs, const float* __restrict__ avd,
    float* __restrict__ tish, float* __restrict__ ccell,
    unsigned short* __restrict__ hprojc, float* __restrict__ a_s2, float* __restrict__ a_d2) {
  int c = blockIdx.x, t = threadIdx.x;
  int tf = t & 127, half = t >> 7;
  __shared__ float mh[8], zh[8];
  __shared__ float sscale[SPL][8];
  __shared__ float msh[8][128];
  __shared__ float b0[128], b1[128], part[2][128], catv[896];
  const int pbase = c * SPL * 8;
  if (t < 8) {
    float mg = -INFINITY;
#pragma unroll
    for (int s = 0; s < SPL; ++s) mg = fmaxf(mg, pm[pbase + s * 8 + t]);
    mh[t] = mg;
  }
  __syncthreads();
  if (t < SPL * 8) {
    int s = t >> 3, h = t & 7;
    float ms = pm[pbase + s * 8 + h];
    sscale[s][h] = (ms > -1e37f) ? __expf(ms - mh[h]) : 0.f;
  }
  __syncthreads();
  if (t < 8) {
    float z = 0.f;
#pragma unroll
    for (int s = 0; s < SPL; ++s) z += pz[pbase + s * 8 + t] * sscale[s][t];
    zh[t] = (z > 0.f) ? 1.f / z : 0.f;
  }
  __syncthreads();
#pragma unroll
  for (int hh = 0; hh < 4; ++hh) {
    int h = half * 4 + hh;
    float a = 0.f;
#pragma unroll
    for (int s = 0; s < SPL; ++s)
      a = fmaf(pmacc[(size_t)(pbase + s * 8 + h) * 128 + tf], sscale[s][h], a);
    msh[h][tf] = a * zh[h];
  }
  __syncthreads();
  {
    int h = tf >> 4;
    float ps = 0.f;
    const float* wp = Wv + (size_t)tf * 128 + half * 64;
    const float* mp = &msh[h][half * 64];
#pragma unroll 4
    for (int k = 0; k < 64; ++k) ps = fmaf(wp[k], mp[k], ps);
    part[half][tf] = ps;
  }
  __syncthreads();
  if (t < 128) b0[t] = part[0][t] + part[1][t] + bv[t];
  __syncthreads();
  int ks = half;
  {
    float ps = 0.f;
    const float* wp = Wot + (size_t)ks * 64 * 128 + tf;
#pragma unroll 4
    for (int k = 0; k < 64; ++k) ps = fmaf(b0[ks * 64 + k], wp[k * 128], ps);
    part[ks][tf] = ps;
  }
  __syncthreads();
  if (t < 128) {
    float vv = part[0][t] + part[1][t] + bo[t];
    b1[t] = vv;
    tish[c * 128 + t] = vv;
  }
  __syncthreads();
  for (int j = t; j < 896; j += 256) {
    float a = bcat[j];
#pragma unroll 4
    for (int k = 0; k < 128; ++k) a = fmaf(b1[k], Wcat_t[k * 896 + j], a);
    catv[j] = a;
  }
  __syncthreads();
  if (t < 128) {
    float td = catv[t];
    float r = 1.f / (1.f + expf(-(catv[128 + t] + catv[512 + t])));
    float zz = 1.f / (1.f + expf(-(catv[256 + t] + catv[640 + t])));
    float nn = tanhf(catv[384 + t] + r * catv[768 + t]);
    float cn = (1.f - zz) * nn + zz * td;
    ccell[c * 128 + t] = cn;
    b0[t] = cn;
  }
  __syncthreads();
  if (gatWt) {
    float ps = 0.f;
    const float* wp = gatWt + (size_t)ks * 64 * 128 + tf;
#pragma unroll 4
    for (int k = 0; k < 64; ++k) ps = fmaf(b0[ks * 64 + k], wp[k * 128], ps);
    part[ks][tf] = ps;
    __syncthreads();
    if (t < 128) {
      float hp = part[0][t] + part[1][t];
      hprojc[c * 128 + t] = f2b(hp);
      float pss = hp * avs[t], pdd = hp * avd[t];
      pss += __shfl_xor(pss, 1); pss += __shfl_xor(pss, 2); pss += __shfl_xor(pss, 4); pss += __shfl_xor(pss, 8);
      pdd += __shfl_xor(pdd, 1); pdd += __shfl_xor(pdd, 2); pdd += __shfl_xor(pdd, 4); pdd += __shfl_xor(pdd, 8);
      if ((t & 15) == 0) {
        a_s2[c * 8 + (t >> 4)] = pss;
        a_d2[c * 8 + (t >> 4)] = pdd;
      }
    }
  }
}

// ---------------- parallel dual-pool partials: grid PB blocks ----------------
__global__ __launch_bounds__(256) void hg_pool(const float* __restrict__ ccell2, const float* __restrict__ tish,
                                               const int* __restrict__ cnt, float* __restrict__ part) {
  int b = blockIdx.x, t = threadIdx.x;
  int c0 = b * (C / PB);
  if (t < 128) {
    float sm = 0.f, mx = -INFINITY;
#pragma unroll 4
    for (int i = 0; i < C / PB; ++i) {
      int c = c0 + i;
      float vv = ccell2[c * 128 + t];
      int n = cnt[c];
      sm += (float)n * vv;
      if (n > 0) mx = fmaxf(mx, vv);
    }
    part[b * 512 + t] = sm;
    part[b * 512 + 128 + t] = mx;
  } else {
    int tt = t - 128;
    float sm = 0.f, mx = -INFINITY;
#pragma unroll 4
    for (int i = 0; i < C / PB; ++i) {
      int c = c0 + i;
      float vv = tish[c * 128 + tt];
      sm += vv;
      mx = fmaxf(mx, vv);
    }
    part[b * 512 + 256 + tt] = sm;
    part[b * 512 + 384 + tt] = mx;
  }
}

// ---------------- classifier MLP (merges pool partials) ----------------
__global__ __launch_bounds__(256) void hg_mlp(const float* __restrict__ part, const float* __restrict__ Wc1t,
                                              const float* __restrict__ bc1, const float* __restrict__ Wc2t,
                                              const float* __restrict__ bc2, const float* __restrict__ Wc3,
                                              const float* __restrict__ bc3, float* __restrict__ outp) {
  __shared__ float emb[512], h1s[256], h2s[128];
  int t = threadIdx.x;
  if (t < 128) {
    float sm = 0.f, mx = -INFINITY;
#pragma unroll
    for (int b = 0; b < PB; ++b) {
      sm += part[b * 512 + t];
      mx = fmaxf(mx, part[b * 512 + 128 + t]);
    }
    emb[t] = sm / (float)N;
    emb[128 + t] = mx;
  } else {
    int tt = t - 128;
    float sm = 0.f, mx = -INFINITY;
#pragma unroll
    for (int b = 0; b < PB; ++b) {
      sm += part[b * 512 + 256 + tt];
      mx = fmaxf(mx, part[b * 512 + 384 + tt]);
    }
    emb[256 + tt] = sm * (1.f / (float)C);
    emb[384 + tt] = mx;
  }
  __syncthreads();
  float a = bc1[t];
#pragma unroll 4
  for (int kk = 0; kk < 512; ++kk) a = fmaf(emb[kk], Wc1t[kk * 256 + t], a);
  h1s[t] = fmaxf(a, 0.f);
  __syncthreads();
  if (t < 128) {
    float a2 = bc2[t];
#pragma unroll 4
    for (int kk = 0; kk < 256; ++kk) a2 = fmaf(h1s[kk], Wc2t[kk * 128 + t], a2);
    h2s[t] = fmaxf(a2, 0.f);
  }
  __syncthreads();
  if (t < 4) {
    float o = bc3[t];
    for (int kk = 0; kk < 128; ++kk) o = fmaf(h2s[kk], Wc3[t * 128 + kk], o);
    outp[t] = o;
  }
}

// ---------------- host launcher ----------------
extern "C" void kernel_launch(void* const* d_in, const int* in_sizes, int n_in,
                              void* d_out, int out_size, void* d_ws, size_t ws_size,
                              hipStream_t stream) {
  (void)in_sizes; (void)n_in; (void)out_size; (void)ws_size;
  const float* feat  = (const float*)d_in[0];
  const int*   eidx  = (const int*)d_in[1];
  const int*   lab   = (const int*)d_in[2];
  const int*   tidx  = (const int*)d_in[3];
  const float* Wcp   = (const float*)d_in[4];
  const float* bcp   = (const float*)d_in[5];
  const float* Wtp   = (const float*)d_in[6];
  const float* btp   = (const float*)d_in[7];
  const float* gatW  = (const float*)d_in[8];
  const float* gasrc = (const float*)d_in[9];
  const float* gadst = (const float*)d_in[10];
  const float* gatb  = (const float*)d_in[11];
  const float* gcnW  = (const float*)d_in[12];
  const float* gcnb  = (const float*)d_in[13];
  const float* buWq  = (const float*)d_in[14];
  const float* buWk  = (const float*)d_in[15];
  const float* buWv  = (const float*)d_in[16];
  const float* bubq  = (const float*)d_in[17];
  const float* bubk  = (const float*)d_in[18];
  const float* bubv  = (const float*)d_in[19];
  const float* buWo  = (const float*)d_in[20];
  const float* bubo  = (const float*)d_in[21];
  const float* tdWv  = (const float*)d_in[22];
  const float* tdbv  = (const float*)d_in[23];
  const float* tdWo  = (const float*)d_in[24];
  const float* tdbo  = (const float*)d_in[25];
  const float* Wih   = (const float*)d_in[26];
  const float* bih   = (const float*)d_in[27];
  const float* Whh   = (const float*)d_in[28];
  const float* bhh   = (const float*)d_in[29];
  const float* Wc1   = (const float*)d_in[30];
  const float* bc1   = (const float*)d_in[31];
  const float* Wc2   = (const float*)d_in[32];
  const float* bc2   = (const float*)d_in[33];
  const float* Wc3   = (const float*)d_in[34];
  const float* bc3   = (const float*)d_in[35];
  float* outp = (float*)d_out;

  const int* csrc = eidx;
  const int* cdst = eidx + E;
  const int* tsrc = tidx;
  const int* tdst = tidx + ET;

  char* w = (char*)d_ws;
  auto alloc = [&](size_t bytes) -> void* {
    void* p = (void*)w;
    w += (bytes + 255) & ~(size_t)255;
    return p;
  };
  char* cnt0 = w;
  int* deg_cell = (int*)alloc((size_t)N * 4);
  int* cur_cell = (int*)alloc((size_t)N * 4);
  int* clu_cnt  = (int*)alloc((size_t)C * 4);
  int* clu_cur  = (int*)alloc((size_t)C * 4);
  size_t cntBytes = (size_t)(w - cnt0);
  int* off_cell = (int*)alloc((size_t)(N + 1) * 4);
  int* btot     = (int*)alloc(64 * 4);
  int* csr      = (int*)alloc((size_t)E * 4);
  int* clu_off  = (int*)alloc((size_t)(C + 1) * 4);
  int* clu_list = (int*)alloc((size_t)N * 4);
  int* toff     = (int*)alloc((size_t)(C + 1) * 4);
  int* tlist    = (int*)alloc((size_t)ET * 4);
  float* dinv   = (float*)alloc((size_t)C * 4);
  unsigned short* buf1 = (unsigned short*)alloc((size_t)N * 128 * 2);  // bf16 cell_h
  unsigned short* buf2 = (unsigned short*)alloc((size_t)N * 128 * 2);  // bf16 hproj
  float* a_s    = (float*)alloc((size_t)N * 8 * 4);
  float* a_d    = (float*)alloc((size_t)N * 8 * 4);
  float* s_att  = (float*)alloc((size_t)N * 8 * 4);
  float* tish   = (float*)alloc((size_t)C * 128 * 4);
  float* qkb    = (float*)alloc((size_t)C * 8 * 128 * 4);
  float* qbb    = (float*)alloc((size_t)C * 8 * 4);
  float* ccell  = (float*)alloc((size_t)C * 128 * 4);
  unsigned short* hprojc = (unsigned short*)alloc((size_t)C * 128 * 2);
  float* a_sc   = (float*)alloc((size_t)C * 8 * 4);
  float* a_dc   = (float*)alloc((size_t)C * 8 * 4);
  float* pm     = (float*)alloc((size_t)C * SPL * 8 * 4);
  float* pz     = (float*)alloc((size_t)C * SPL * 8 * 4);
  float* pmacc  = (float*)alloc((size_t)C * SPL * 8 * 128 * 4);
  float* poolp  = (float*)alloc((size_t)PB * 512 * 4);
  float* A_td   = (float*)alloc(128 * 128 * 4);
  float* Wcat_t = (float*)alloc(128 * 896 * 4);
  float* bcat   = (float*)alloc(896 * 4);
  short* Wcompb = (short*)alloc(128 * 256 * 2);   // bf16 composite weight [j][k]
  float* bcomp  = (float*)alloc(128 * 4);
  float* Wtpt   = (float*)alloc(256 * 128 * 4);
  float* g1t    = (float*)alloc(128 * 128 * 4);
  float* g2t    = (float*)alloc(128 * 128 * 4);
  float* Wqt    = (float*)alloc(128 * 128 * 4);
  float* Wot    = (float*)alloc(128 * 128 * 4);
  float* gatW2t = (float*)alloc(128 * 128 * 4);
  float* Wc1t   = (float*)alloc(512 * 256 * 4);
  float* Wc2t   = (float*)alloc(256 * 128 * 4);

  hipMemsetAsync(cnt0, 0, cntBytes, stream);

  hg_hist<<<(E + 255) / 256, 256, 0, stream>>>(cdst, deg_cell, lab, clu_cnt);
  hg_scan1<<<NB, 256, 0, stream>>>(deg_cell, off_cell, btot, N);
  hg_scan2_setup<<<3, 256, 0, stream>>>(btot, off_cell, clu_cnt, clu_off, tsrc, tdst, toff, tlist, dinv);
  hg_scan3<<<NB, 256, 0, stream>>>(off_cell, btot, N);
  hg_scatter<<<(E + 255) / 256, 256, 0, stream>>>(csrc, cdst, off_cell, cur_cell, csr,
                                                  lab, clu_off, clu_cur, clu_list);

  PrepArgs pa;
  pa.j[0] = {Wtp,            Wtpt,   128, 256, 128};
  pa.j[1] = {gcnW,           g1t,    128, 128, 128};
  pa.j[2] = {gcnW + 128*128, g2t,    128, 128, 128};
  pa.j[3] = {buWq,           Wqt,    128, 128, 128};
  pa.j[4] = {buWo,           Wot,    128, 128, 128};
  pa.j[5] = {gatW + 128*128, gatW2t, 128, 128, 128};
  pa.j[6] = {Wc1,            Wc1t,   256, 512, 256};
  pa.j[7] = {Wc2,            Wc2t,   128, 256, 128};
  pa.gatW1 = gatW; pa.Wcp = Wcp; pa.bcp = bcp; pa.Wcompb = Wcompb; pa.bcomp = bcomp;
  pa.tdWo = tdWo; pa.tdWv = tdWv; pa.tdbv = tdbv; pa.tdbo = tdbo;
  pa.A_td = A_td; pa.Wcat_t = Wcat_t; pa.bcat = bcat;
  hg_prep1<<<dim3(128, 10), 256, 0, stream>>>(pa);
  hg_pc2b<<<384, 256, 0, stream>>>(Wih, bih, Whh, bhh, A_td, Wcat_t, bcat);

  const int RT = (N + 127) / 128;  // 469 row tiles
  hg_gemm_coef<<<RT + C, 256, 0, stream>>>(feat, N, RT, Wcompb, bcomp, buf2, gasrc, gadst, a_s, a_d,
                                           clu_list, clu_off, Wtpt, btp, tish);
  // ---- layer 1 ----
  hg_gcn_q<<<C, 128, 0, stream>>>(tish, toff, tlist, dinv, g1t, gcnb, Wqt, bubq, buWk, bubk, qkb, qbb);
  hg_gat_agg<<<(N + 3) / 4, 256, 0, stream>>>(buf2, a_s, a_d, nullptr, off_cell, csr, gatb, buf1,
                                              qkb, qbb, lab, clu_list, s_att, N);
  hg_bu_part<<<dim3(C, SPL), 256, 0, stream>>>(s_att, buf1, clu_list, clu_off, pm, pz, pmacc);
  hg_bu_chain<<<C, 256, 0, stream>>>(pm, pz, pmacc, buWv, bubv, Wot, bubo, Wcat_t, bcat,
                                     gatW2t, gasrc + 128, gadst + 128, tish, ccell, hprojc, a_sc, a_dc);
  // ---- layer 2 ----
  hg_gcn_q<<<C, 128, 0, stream>>>(tish, toff, tlist, dinv, g2t, gcnb + 128, Wqt, bubq, buWk, bubk, qkb, qbb);
  hg_gat_agg<<<(N + 3) / 4, 256, 0, stream>>>(hprojc, a_sc, a_dc, lab, off_cell, csr, gatb + 128, buf1,
                                              qkb, qbb, lab, clu_list, s_att, N);
  hg_bu_part<<<dim3(C, SPL), 256, 0, stream>>>(s_att, buf1, clu_list, clu_off, pm, pz, pmacc);
  hg_bu_chain<<<C, 256, 0, stream>>>(pm, pz, pmacc, buWv, bubv, Wot, bubo, Wcat_t, bcat,
                                     nullptr, nullptr, nullptr, tish, ccell, nullptr, nullptr, nullptr);

  hg_pool<<<PB, 256, 0, stream>>>(ccell, tish, clu_cnt, poolp);
  hg_mlp<<<1, 256, 0, stream>>>(poolp, Wc1t, bc1, Wc2t, bc2, Wc3, bc3, outp);
}

// Round 14
// 542.877 us; speedup vs baseline: 1.0699x; 1.0070x over previous
//
#include <hip/hip_runtime.h>
#include <math.h>

constexpr int N  = 60000;
constexpr int F  = 256;
constexpr int H  = 128;
constexpr int C  = 256;
constexpr int E  = 600000;
constexpr int ET = 1500;
constexpr int NB = (N + 1023) / 1024;  // 59 scan blocks
constexpr int SPL = 8;                 // bu softmax splits per cluster
constexpr int PB  = 16;                // pooling blocks

typedef __attribute__((ext_vector_type(8))) short short8;
typedef __attribute__((ext_vector_type(4))) float f32x4;

__device__ __forceinline__ unsigned short f2b(float f) {  // fp32 -> bf16 (RNE)
  unsigned int u = __float_as_uint(f);
  return (unsigned short)((u + 0x7FFFu + ((u >> 16) & 1u)) >> 16);
}
__device__ __forceinline__ float b2f(unsigned short b) {
  return __uint_as_float(((unsigned int)b) << 16);
}

// ---------------- histograms (cell-dst degree + cluster counts) ----------------
__global__ void hg_hist(const int* __restrict__ cdst, int* __restrict__ deg,
                        const int* __restrict__ lab, int* __restrict__ ccnt) {
  int e = blockIdx.x * 256 + threadIdx.x;
  if (e < E) atomicAdd(&deg[cdst[e]], 1);
  if (e < N) atomicAdd(&ccnt[lab[e]], 1);
}

// ---------------- multi-block scan ----------------
__global__ __launch_bounds__(256) void hg_scan1(const int* __restrict__ deg, int* __restrict__ off,
                                                int* __restrict__ btot, int n) {
  int b = blockIdx.x, t = threadIdx.x;
  int i0 = b * 1024 + t * 4;
  __shared__ int sums[256];
  int d0 = 0, d1 = 0, d2 = 0, d3 = 0;
  if (i0 + 3 < n) {
    int4 dd = *(const int4*)&deg[i0];
    d0 = dd.x; d1 = dd.y; d2 = dd.z; d3 = dd.w;
  } else {
    if (i0     < n) d0 = deg[i0];
    if (i0 + 1 < n) d1 = deg[i0 + 1];
    if (i0 + 2 < n) d2 = deg[i0 + 2];
    if (i0 + 3 < n) d3 = deg[i0 + 3];
  }
  int s = d0 + d1 + d2 + d3;
  sums[t] = s;
  __syncthreads();
  for (int ofs = 1; ofs < 256; ofs <<= 1) {
    int v = (t >= ofs) ? sums[t - ofs] : 0;
    __syncthreads();
    sums[t] += v;
    __syncthreads();
  }
  int excl = sums[t] - s;
  if (t == 255) btot[b] = sums[t];
  int run = excl;
  if (i0     < n) off[i0]     = run; run += d0;
  if (i0 + 1 < n) off[i0 + 1] = run; run += d1;
  if (i0 + 2 < n) off[i0 + 2] = run; run += d2;
  if (i0 + 3 < n) off[i0 + 3] = run;
}

// block0: scan of btot; block1: cluster-count scan; block2: tissue CSR + dinv
__global__ __launch_bounds__(256) void hg_scan2_setup(int* __restrict__ btot, int* __restrict__ off,
                                                      const int* __restrict__ ccnt, int* __restrict__ coff,
                                                      const int* __restrict__ tsrc, const int* __restrict__ tdst,
                                                      int* __restrict__ toff, int* __restrict__ tlist,
                                                      float* __restrict__ dinv) {
  __shared__ int sa[256], sb[256], sc2[256];
  int t = threadIdx.x;
  if (blockIdx.x == 0) {
    if (t < 64) sa[t] = (t < NB) ? btot[t] : 0;
    __syncthreads();
    if (t == 0) {
      int r = 0;
      for (int i = 0; i < NB; ++i) { int v = sa[i]; sa[i] = r; r += v; }
      off[N] = r;
    }
    __syncthreads();
    if (t < NB) btot[t] = sa[t];
  } else if (blockIdx.x == 1) {
    int v0 = ccnt[t];
    sa[t] = v0;
    __syncthreads();
    for (int ofs = 1; ofs < 256; ofs <<= 1) {
      int v = (t >= ofs) ? sa[t - ofs] : 0;
      __syncthreads();
      sa[t] += v;
      __syncthreads();
    }
    coff[t + 1] = sa[t];
    if (t == 0) coff[0] = 0;
  } else {
    sa[t] = 0;
    __syncthreads();
    for (int e = t; e < ET; e += 256) atomicAdd(&sa[tdst[e]], 1);
    __syncthreads();
    int v = sa[t];
    dinv[t] = rsqrtf((float)(v + 1));
    sb[t] = v;
    __syncthreads();
    for (int ofs = 1; ofs < 256; ofs <<= 1) {
      int u = (t >= ofs) ? sb[t - ofs] : 0;
      __syncthreads();
      sb[t] += u;
      __syncthreads();
    }
    toff[t + 1] = sb[t];
    if (t == 0) toff[0] = 0;
    sc2[t] = sb[t] - v;
    __syncthreads();
    for (int e = t; e < ET; e += 256) {
      int d = tdst[e];
      int p = atomicAdd(&sc2[d], 1);
      tlist[p] = tsrc[e];
    }
  }
}

__global__ void hg_scan3(int* __restrict__ off, const int* __restrict__ btot, int n) {
  int b = blockIdx.x;
  int addv = btot[b];
  int i0 = b * 1024 + threadIdx.x * 4;
#pragma unroll
  for (int r = 0; r < 4; ++r)
    if (i0 + r < n) off[i0 + r] += addv;
}

// merged: cell-edge CSR scatter + cluster-list scatter
__global__ void hg_scatter(const int* __restrict__ csrc, const int* __restrict__ cdst,
                           const int* __restrict__ off, int* __restrict__ cur, int* __restrict__ csr,
                           const int* __restrict__ lab, const int* __restrict__ coff,
                           int* __restrict__ ccur, int* __restrict__ list) {
  int e = blockIdx.x * 256 + threadIdx.x;
  if (e < E) {
    int d = cdst[e];
    int p = atomicAdd(&cur[d], 1);
    csr[off[d] + p] = csrc[e];
  }
  if (e < N) {
    int c = lab[e];
    int p = atomicAdd(&ccur[c], 1);
    list[coff[c] + p] = e;
  }
}

// ---------------- prep: 8 transposes + pc0(bf16) + pc1 (grid y = job) ----------------
struct TJob { const float* src; float* dst; int SR; int SC; int dld; };
struct PrepArgs {
  TJob j[8];
  const float* gatW1; const float* Wcp; const float* bcp; short* Wcompb; float* bcomp;
  const float* tdWo; const float* tdWv; const float* tdbv; const float* tdbo;
  float* A_td; float* Wcat_t; float* bcat;
};

__global__ __launch_bounds__(256) void hg_prep1(PrepArgs a) {
  int y = blockIdx.y, t = threadIdx.x;
  if (y < 8) {
    TJob jb = a.j[y];
    int total = jb.SR * jb.SC;
    for (int idx = blockIdx.x * 256 + t; idx < total; idx += gridDim.x * 256) {
      int r = idx / jb.SC, c = idx - r * jb.SC;
      jb.dst[(size_t)c * jb.dld + r] = jb.src[idx];
    }
  } else if (y == 8) {
    // pc0: Wcomp[j][k] = sum_m gatW1[j][m]*Wcp[m][k]  (bf16, j-major for MFMA B frags)
    int j = blockIdx.x, k = t;
    float acc = 0.f;
#pragma unroll 4
    for (int m = 0; m < 128; ++m) acc = fmaf(a.gatW1[j * 128 + m], a.Wcp[m * 256 + k], acc);
    a.Wcompb[(size_t)j * 256 + k] = (short)f2b(acc);
    if (k == 0) {
      float b = 0.f;
      for (int m = 0; m < 128; ++m) b = fmaf(a.gatW1[j * 128 + m], a.bcp[m], b);
      a.bcomp[j] = b;
    }
  } else if (blockIdx.x < 64) {
    int j = blockIdx.x * 2 + (t >> 7), k = t & 127;
    float acc = 0.f;
#pragma unroll 4
    for (int p = 0; p < 128; ++p) acc = fmaf(a.tdWo[j * 128 + p], a.tdWv[p * 128 + k], acc);
    a.A_td[j * 128 + k] = acc;
    a.Wcat_t[k * 896 + j] = acc;
    if (k == 0) {
      float b = 0.f;
      for (int p = 0; p < 128; ++p) b = fmaf(a.tdWo[j * 128 + p], a.tdbv[p], b);
      a.bcat[j] = b + a.tdbo[j];
    }
  }
}

__global__ __launch_bounds__(256) void hg_pc2b(const float* __restrict__ Wih, const float* __restrict__ bih,
                                               const float* __restrict__ Whh, const float* __restrict__ bhh,
                                               const float* __restrict__ A_td, float* __restrict__ Wcat_t,
                                               float* __restrict__ bcat) {
  int jj = blockIdx.x * 2 + (threadIdx.x >> 7), k = threadIdx.x & 127;
  const float* coef;
  float extra, bb;
  int dcol, j;
  if (jj < 384) {
    j = jj; coef = Wih + (size_t)j * 256; extra = Wih[(size_t)j * 256 + 128 + k]; dcol = 128 + j; bb = bih[j];
  } else {
    j = jj - 384; coef = Whh + (size_t)j * 128; extra = 0.f; dcol = 512 + j; bb = bhh[j];
  }
  float a = 0.f;
#pragma unroll 4
  for (int m = 0; m < 128; ++m) a = fmaf(coef[m], A_td[m * 128 + k], a);
  Wcat_t[k * 896 + dcol] = a + extra;
  if (k == 0) {
    float b = 0.f;
    for (int m = 0; m < 128; ++m) b = fmaf(coef[m], bcat[m], b);
    bcat[dcol] = b + bb;
  }
}

// ---------------- MFMA bf16 GEMM (K=256, tile 128x128, no LDS) + GAT-coef epilogue ----------------
__global__ __launch_bounds__(256, 3) void hg_gemm_coef(
    const float* __restrict__ A, int M, int rtiles,
    const short* __restrict__ Wb,          // bf16 [128][256] j-major
    const float* __restrict__ bias,
    unsigned short* __restrict__ outp,     // bf16 [M][128]
    const float* __restrict__ avs, const float* __restrict__ avd,
    float* __restrict__ o_s, float* __restrict__ o_d,
    const int* __restrict__ list, const int* __restrict__ coff,
    const float* __restrict__ Wtpt, const float* __restrict__ btp, float* __restrict__ tish) {
  __shared__ float mrow[256];
  const int t = threadIdx.x;

  if (blockIdx.x >= rtiles) {
    // ---- tissue init: per-cluster mean + projection (fp32) ----
    int c = blockIdx.x - rtiles;
    int s0 = coff[c], n = coff[c + 1] - s0;
    float acc = 0.f;
#pragma unroll 4
    for (int i = 0; i < n; ++i) acc += A[(size_t)list[s0 + i] * F + t];
    mrow[t] = acc / fmaxf((float)n, 1.f);
    __syncthreads();
    if (t < 128) {
      float a = btp[t];
#pragma unroll 4
      for (int k = 0; k < 256; ++k) a = fmaf(mrow[k], Wtpt[k * 128 + t], a);
      tish[c * 128 + t] = a;
    }
    return;
  }

  const int w = t >> 6, l = t & 63;
  const int li = l & 15, lk = l >> 4;   // li: row/col within 16-tile, lk: k-group
  const int m0 = blockIdx.x * 128 + w * 32;

  f32x4 zero = {0.f, 0.f, 0.f, 0.f};
  f32x4 acc[2][8];
#pragma unroll
  for (int rt = 0; rt < 2; ++rt)
#pragma unroll
    for (int ct = 0; ct < 8; ++ct) acc[rt][ct] = zero;

  const int r0 = m0 + li, r1 = m0 + 16 + li;
  const bool v0 = r0 < M, v1 = r1 < M;
  const float* a0p = A + (size_t)r0 * 256 + lk * 8;
  const float* a1p = A + (size_t)r1 * 256 + lk * 8;

  for (int kc = 0; kc < 256; kc += 32) {
    short8 bf[8];
#pragma unroll
    for (int ct = 0; ct < 8; ++ct)
      bf[ct] = *(const short8*)&Wb[(size_t)(ct * 16 + li) * 256 + kc + lk * 8];
    short8 af0 = {0, 0, 0, 0, 0, 0, 0, 0};
    short8 af1 = {0, 0, 0, 0, 0, 0, 0, 0};
    if (v0) {
      float4 x = *(const float4*)(a0p + kc);
      float4 y = *(const float4*)(a0p + kc + 4);
      af0[0] = (short)f2b(x.x); af0[1] = (short)f2b(x.y); af0[2] = (short)f2b(x.z); af0[3] = (short)f2b(x.w);
      af0[4] = (short)f2b(y.x); af0[5] = (short)f2b(y.y); af0[6] = (short)f2b(y.z); af0[7] = (short)f2b(y.w);
    }
    if (v1) {
      float4 x = *(const float4*)(a1p + kc);
      float4 y = *(const float4*)(a1p + kc + 4);
      af1[0] = (short)f2b(x.x); af1[1] = (short)f2b(x.y); af1[2] = (short)f2b(x.z); af1[3] = (short)f2b(x.w);
      af1[4] = (short)f2b(y.x); af1[5] = (short)f2b(y.y); af1[6] = (short)f2b(y.z); af1[7] = (short)f2b(y.w);
    }
#pragma unroll
    for (int ct = 0; ct < 8; ++ct) {
      acc[0][ct] = __builtin_amdgcn_mfma_f32_16x16x32_bf16(af0, bf[ct], acc[0][ct], 0, 0, 0);
      acc[1][ct] = __builtin_amdgcn_mfma_f32_16x16x32_bf16(af1, bf[ct], acc[1][ct], 0, 0, 0);
    }
  }

  // epilogue: bias, bf16 store, per-head coef dots (row-outer so o_s/o_d writes coalesce)
#pragma unroll
  for (int rt = 0; rt < 2; ++rt) {
#pragma unroll
    for (int r = 0; r < 4; ++r) {
      int gm = m0 + rt * 16 + lk * 4 + r;
      float psv[8], pdv[8];
#pragma unroll
      for (int ct = 0; ct < 8; ++ct) {
        float v = acc[rt][ct][r] + bias[ct * 16 + li];
        if (gm < M) outp[(size_t)gm * 128 + ct * 16 + li] = f2b(v);
        float ps = v * avs[ct * 16 + li], pd = v * avd[ct * 16 + li];
        ps += __shfl_xor(ps, 1); ps += __shfl_xor(ps, 2); ps += __shfl_xor(ps, 4); ps += __shfl_xor(ps, 8);
        pd += __shfl_xor(pd, 1); pd += __shfl_xor(pd, 2); pd += __shfl_xor(pd, 4); pd += __shfl_xor(pd, 8);
        psv[ct] = ps;
        pdv[ct] = pd;
      }
      if (li == 0 && gm < M) {
        float* osp = o_s + (size_t)gm * 8;
        float* odp = o_d + (size_t)gm * 8;
        *(float4*)osp       = make_float4(psv[0], psv[1], psv[2], psv[3]);
        *(float4*)(osp + 4) = make_float4(psv[4], psv[5], psv[6], psv[7]);
        *(float4*)odp       = make_float4(pdv[0], pdv[1], pdv[2], pdv[3]);
        *(float4*)(odp + 4) = make_float4(pdv[4], pdv[5], pdv[6], pdv[7]);
      }
    }
  }
}

// ---------------- GAT aggregation: one WAVE per node, bf16 gathers, XCD-swizzled grid ----------------
#define GMAXE 64
constexpr int NWG_AGG = (N + 3) / 4;  // 15000, divisible by 8
__global__ __launch_bounds__(256) void hg_gat_agg(
    const unsigned short* __restrict__ hproj, const float* __restrict__ a_s,
    const float* __restrict__ a_d, const int* __restrict__ remap,
    const int* __restrict__ off, const int* __restrict__ csr,
    const float* __restrict__ bias, unsigned short* __restrict__ outh,
    const float* __restrict__ qk, const float* __restrict__ qb,
    const int* __restrict__ lab, const int* __restrict__ nodelist,
    float* __restrict__ satt, int nNodes) {
  const int wid = threadIdx.x >> 6;
  const int l = threadIdx.x & 63;
  // bijective XCD-aware swizzle: consecutive swizzled blocks stay on one XCD's L2
  const int bidx = blockIdx.x;
  const int sb = (NWG_AGG % 8 == 0) ? ((bidx & 7) * (NWG_AGG / 8) + (bidx >> 3)) : bidx;
  const int gid = sb * 4 + wid;
  __shared__ int srcs_s[4][GMAXE];
  __shared__ float w_s[4][GMAXE][8];
  if (gid >= nNodes) return;
  const int node = nodelist[gid];
  int* srcs = srcs_s[wid];
  float (*wls)[8] = w_s[wid];
  const int o0 = off[node], deg = off[node + 1] - o0;
  const int cl = lab[node];
  const int dl = remap ? cl : node;
  const int hsc = l & 7;
  const int q4 = l & 31;
  const int sub = l >> 5;
  const int hq = q4 >> 2;
  const float adh = a_d[dl * 8 + hsc];
  const float ash = a_s[dl * 8 + hsc];
  float msc = -INFINITY, zsc = 0.f;
  float4 acc = make_float4(0.f, 0.f, 0.f, 0.f);
  const ushort4* hp4 = (const ushort4*)hproj;  // 4 bf16 per element

  for (int cb = 0; cb < deg; cb += GMAXE) {
    const int len = min(GMAXE, deg - cb);
    if (l < len) {
      int s = csr[o0 + cb + l];
      srcs[l] = remap ? remap[s] : s;
    }
    asm volatile("s_waitcnt lgkmcnt(0)" ::: "memory");
    float lm = -INFINITY;
    for (int base = 0; base < len; base += 8) {
      int e = base + (l >> 3);
      if (e < len) {
        float sc = a_s[srcs[e] * 8 + hsc] + adh;
        sc = sc > 0.f ? sc : 0.2f * sc;
        wls[e][hsc] = sc;
        lm = fmaxf(lm, sc);
      }
    }
    lm = fmaxf(lm, __shfl_xor(lm, 8));
    lm = fmaxf(lm, __shfl_xor(lm, 16));
    lm = fmaxf(lm, __shfl_xor(lm, 32));
    float mnew = fmaxf(msc, lm);
    float rs = __expf(msc - mnew);
    float zc = 0.f;
    asm volatile("s_waitcnt lgkmcnt(0)" ::: "memory");
    for (int base = 0; base < len; base += 8) {
      int e = base + (l >> 3);
      if (e < len) {
        float wv = __expf(wls[e][hsc] - mnew);
        wls[e][hsc] = wv;
        zc += wv;
      }
    }
    asm volatile("s_waitcnt lgkmcnt(0)" ::: "memory");
    zc += __shfl_xor(zc, 8); zc += __shfl_xor(zc, 16); zc += __shfl_xor(zc, 32);
    zsc = zsc * rs + zc;
    msc = mnew;
    float rsa = __shfl(rs, hq);
    acc.x *= rsa; acc.y *= rsa; acc.z *= rsa; acc.w *= rsa;
    for (int e = sub; e < len; e += 2) {
      float wv = wls[e][hq];
      ushort4 hv = hp4[(size_t)srcs[e] * 32 + q4];
      acc.x = fmaf(wv, b2f(hv.x), acc.x);
      acc.y = fmaf(wv, b2f(hv.y), acc.y);
      acc.z = fmaf(wv, b2f(hv.z), acc.z);
      acc.w = fmaf(wv, b2f(hv.w), acc.w);
    }
  }
  float ssl = ash + adh;
  ssl = ssl > 0.f ? ssl : 0.2f * ssl;
  float mnew = fmaxf(msc, ssl);
  float rs = __expf(msc - mnew);
  float wsl = __expf(ssl - mnew);
  zsc = zsc * rs + wsl;
  float rsa = __shfl(rs, hq);
  float wsa = __shfl(wsl, hq);
  float zh = __shfl(zsc, hq);
  acc.x *= rsa; acc.y *= rsa; acc.z *= rsa; acc.w *= rsa;
  acc.x += __shfl_xor(acc.x, 32);
  acc.y += __shfl_xor(acc.y, 32);
  acc.z += __shfl_xor(acc.z, 32);
  acc.w += __shfl_xor(acc.w, 32);
  ushort4 hvs = hp4[(size_t)dl * 32 + q4];
  acc.x = fmaf(wsa, b2f(hvs.x), acc.x);
  acc.y = fmaf(wsa, b2f(hvs.y), acc.y);
  acc.z = fmaf(wsa, b2f(hvs.z), acc.z);
  acc.w = fmaf(wsa, b2f(hvs.w), acc.w);
  float inv = 1.f / zh;
  float4 bv4 = *(const float4*)&bias[q4 * 4];
  float4 o;
  o.x = acc.x * inv + bv4.x;
  o.y = acc.y * inv + bv4.y;
  o.z = acc.z * inv + bv4.z;
  o.w = acc.w * inv + bv4.w;
  o.x = o.x > 0.f ? o.x : __expf(o.x) - 1.f;
  o.y = o.y > 0.f ? o.y : __expf(o.y) - 1.f;
  o.z = o.z > 0.f ? o.z : __expf(o.z) - 1.f;
  o.w = o.w > 0.f ? o.w : __expf(o.w) - 1.f;
  if (sub == 0) {
    ushort4 ov = make_ushort4(f2b(o.x), f2b(o.y), f2b(o.z), f2b(o.w));
    ((ushort4*)outh)[(size_t)node * 32 + q4] = ov;
  }

  // s_att epilogue (qk L2-hot via clu_list ordering + XCD swizzle)
  const float4* qk4 = (const float4*)(qk + (size_t)cl * 1024);
  float p0, p1, p2, p3;
  {
    float4 qv0 = qk4[(sub * 4 + 0) * 32 + q4];
    float4 qv1 = qk4[(sub * 4 + 1) * 32 + q4];
    float4 qv2 = qk4[(sub * 4 + 2) * 32 + q4];
    float4 qv3 = qk4[(sub * 4 + 3) * 32 + q4];
    p0 = o.x * qv0.x + o.y * qv0.y + o.z * qv0.z + o.w * qv0.w;
    p1 = o.x * qv1.x + o.y * qv1.y + o.z * qv1.z + o.w * qv1.w;
    p2 = o.x * qv2.x + o.y * qv2.y + o.z * qv2.z + o.w * qv2.w;
    p3 = o.x * qv3.x + o.y * qv3.y + o.z * qv3.z + o.w * qv3.w;
  }
  int b4f = (l >> 4) & 1, b3f = (l >> 3) & 1;
  float snd0 = b4f ? p0 : p2, snd1 = b4f ? p1 : p3;
  float kp0  = b4f ? p2 : p0, kp1  = b4f ? p3 : p1;
  kp0 += __shfl_xor(snd0, 16);
  kp1 += __shfl_xor(snd1, 16);
  float snd = b3f ? kp0 : kp1;
  float kp  = b3f ? kp1 : kp0;
  kp += __shfl_xor(snd, 8);
  kp += __shfl_xor(kp, 4);
  kp += __shfl_xor(kp, 2);
  kp += __shfl_xor(kp, 1);
  int h = sub * 4 + b4f * 2 + b3f;
  if ((l & 7) == 0) satt[(size_t)node * 8 + h] = kp + qb[cl * 8 + h];
}

// ---------------- tissue GCN + q projection + qk/qb tables ----------------
__global__ __launch_bounds__(128) void hg_gcn_q(const float* __restrict__ tin, const int* __restrict__ toff,
                                                const int* __restrict__ tlist, const float* __restrict__ dinv,
                                                const float* __restrict__ gt, const float* __restrict__ gcnb,
                                                const float* __restrict__ Wqt, const float* __restrict__ bq,
                                                const float* __restrict__ Wk, const float* __restrict__ bk,
                                                float* __restrict__ qk, float* __restrict__ qb) {
  int c = blockIdx.x, t = threadIdx.x;
  __shared__ float xa[128], trow[128], qrow[128];
  float dc = dinv[c];
  float acc = tin[c * 128 + t] * dc * dc;
  int s0 = toff[c], s1 = toff[c + 1];
  for (int i = s0; i < s1; ++i) {
    int s = tlist[i];
    acc = fmaf(tin[s * 128 + t], dinv[s] * dc, acc);
  }
  xa[t] = acc;
  __syncthreads();
  float th = 0.f;
#pragma unroll 4
  for (int k = 0; k < 128; ++k) th = fmaf(xa[k], gt[k * 128 + t], th);
  float vv = fmaxf(th + gcnb[t], 0.f);
  trow[t] = vv;
  __syncthreads();
  float qa = bq[t];
#pragma unroll 4
  for (int k = 0; k < 128; ++k) qa = fmaf(trow[k], Wqt[k * 128 + t], qa);
  qrow[t] = qa * 0.25f;  // 1/sqrt(DH)
  __syncthreads();
#pragma unroll
  for (int h = 0; h < 8; ++h) {
    float s = 0.f;
#pragma unroll
    for (int j = 0; j < 16; ++j) s = fmaf(Wk[(size_t)(h * 16 + j) * 128 + t], qrow[h * 16 + j], s);
    qk[((size_t)c * 8 + h) * 128 + t] = s;
  }
  if (t < 8) {
    float s = 0.f;
#pragma unroll
    for (int j = 0; j < 16; ++j) s = fmaf(qrow[t * 16 + j], bk[t * 16 + j], s);
    qb[c * 8 + t] = s;
  }
}

// ---------------- bu softmax partials: grid (C, SPL), bf16 gathers ----------------
__global__ __launch_bounds__(256) void hg_bu_part(
    const float* __restrict__ s_att, const unsigned short* __restrict__ hcell,
    const int* __restrict__ list, const int* __restrict__ coff,
    float* __restrict__ pm, float* __restrict__ pz, float* __restrict__ pmacc) {
  int c = blockIdx.x, sp = blockIdx.y, t = threadIdx.x;
  int s0 = coff[c], n = coff[c + 1] - s0;
  int chunk = (n + SPL - 1) / SPL;
  int b0 = min(n, sp * chunk), b1 = min(n, b0 + chunk);
  int cnt = b1 - b0;
  int tf = t & 127, half = t >> 7;
  __shared__ float red[32][8];
  __shared__ float mh[8];
  __shared__ int cells[64];
  __shared__ float wl[64][8];
  __shared__ float msh[8][128];
  int g = t >> 3, h8 = t & 7;
  float lm = -INFINITY;
  for (int i = g; i < cnt; i += 32) lm = fmaxf(lm, s_att[(size_t)list[s0 + b0 + i] * 8 + h8]);
  red[g][h8] = lm;
  __syncthreads();
  if (t < 8) {
    float m2 = -INFINITY;
#pragma unroll
    for (int i = 0; i < 32; ++i) m2 = fmaxf(m2, red[i][t]);
    mh[t] = m2;
  }
  __syncthreads();
  const float mloc = mh[t & 7];
  float zp = 0.f;
  float macc[8] = {0.f, 0.f, 0.f, 0.f, 0.f, 0.f, 0.f, 0.f};
  for (int cb = 0; cb < cnt; cb += 64) {
    int len = min(64, cnt - cb);
    if (t < len) cells[t] = list[s0 + b0 + cb + t];
    __syncthreads();
#pragma unroll
    for (int p = 0; p < 2; ++p) {
      int e = p * 32 + (t >> 3);
      if (e < len) {
        float w = __expf(s_att[(size_t)cells[e] * 8 + (t & 7)] - mloc);
        wl[e][t & 7] = w;
        zp += w;
      }
    }
    __syncthreads();
    for (int e = half; e < len; e += 2) {
      float x = b2f(hcell[(size_t)cells[e] * 128 + tf]);
      float4 w0 = *(const float4*)&wl[e][0];
      float4 w1 = *(const float4*)&wl[e][4];
      macc[0] = fmaf(w0.x, x, macc[0]);
      macc[1] = fmaf(w0.y, x, macc[1]);
      macc[2] = fmaf(w0.z, x, macc[2]);
      macc[3] = fmaf(w0.w, x, macc[3]);
      macc[4] = fmaf(w1.x, x, macc[4]);
      macc[5] = fmaf(w1.y, x, macc[5]);
      macc[6] = fmaf(w1.z, x, macc[6]);
      macc[7] = fmaf(w1.w, x, macc[7]);
    }
    __syncthreads();
  }
  red[t >> 3][t & 7] = zp;
  __syncthreads();
  int pidx = (c * SPL + sp) * 8;
  if (t < 8) {
    float z = 0.f;
#pragma unroll
    for (int i = 0; i < 32; ++i) z += red[i][t];
    pz[pidx + t] = z;
    pm[pidx + t] = mh[t];
  }
  if (half) {
#pragma unroll
    for (int h = 0; h < 8; ++h) msh[h][tf] = macc[h];
  }
  __syncthreads();
  if (!half) {
#pragma unroll
    for (int h = 0; h < 8; ++h) pmacc[(size_t)(pidx + h) * 128 + tf] = macc[h] + msh[h][tf];
  }
}

// ---------------- fused cluster chain: merge partials, Wv, Wo, td+GRU, gates, next GAT proj ----------------
__global__ __launch_bounds__(256) void hg_bu_chain(
    const float* __restrict__ pm, const float* __restrict__ pz, const float* __restrict__ pmacc,
    const float* __restrict__ Wv, const float* __restrict__ bv,
    const float* __restrict__ Wot, const float* __restrict__ bo,
    const float* __restrict__ Wcat_t, const float* __restrict__ bcat,
    const float* __restrict__ gatWt, const float* __restrict__ avs, const float* __restrict__ avd,
    float* __restrict__ tish, float* __restrict__ ccell,
    unsigned short* __restrict__ hprojc, float* __restrict__ a_s2, float* __restrict__ a_d2) {
  int c = blockIdx.x, t = threadIdx.x;
  int tf = t & 127, half = t >> 7;
  __shared__ float mh[8], zh[8];
  __shared__ float sscale[SPL][8];
  __shared__ float msh[8][128];
  __shared__ float b0[128], b1[128], part[2][128], catv[896];
  const int pbase = c * SPL * 8;
  if (t < 8) {
    float mg = -INFINITY;
#pragma unroll
    for (int s = 0; s < SPL; ++s) mg = fmaxf(mg, pm[pbase + s * 8 + t]);
    mh[t] = mg;
  }
  __syncthreads();
  if (t < SPL * 8) {
    int s = t >> 3, h = t & 7;
    float ms = pm[pbase + s * 8 + h];
    sscale[s][h] = (ms > -1e37f) ? __expf(ms - mh[h]) : 0.f;
  }
  __syncthreads();
  if (t < 8) {
    float z = 0.f;
#pragma unroll
    for (int s = 0; s < SPL; ++s) z += pz[pbase + s * 8 + t] * sscale[s][t];
    zh[t] = (z > 0.f) ? 1.f / z : 0.f;
  }
  __syncthreads();
#pragma unroll
  for (int hh = 0; hh < 4; ++hh) {
    int h = half * 4 + hh;
    float a = 0.f;
#pragma unroll
    for (int s = 0; s < SPL; ++s)
      a = fmaf(pmacc[(size_t)(pbase + s * 8 + h) * 128 + tf], sscale[s][h], a);
    msh[h][tf] = a * zh[h];
  }
  __syncthreads();
  {
    int h = tf >> 4;
    float ps = 0.f;
    const float* wp = Wv + (size_t)tf * 128 + half * 64;
    const float* mp = &msh[h][half * 64];
#pragma unroll 4
    for (int k = 0; k < 64; ++k) ps = fmaf(wp[k], mp[k], ps);
    part[half][tf] = ps;
  }
  __syncthreads();
  if (t < 128) b0[t] = part[0][t] + part[1][t] + bv[t];
  __syncthreads();
  int ks = half;
  {
    float ps = 0.f;
    const float* wp = Wot + (size_t)ks * 64 * 128 + tf;
#pragma unroll 4
    for (int k = 0; k < 64; ++k) ps = fmaf(b0[ks * 64 + k], wp[k * 128], ps);
    part[ks][tf] = ps;
  }
  __syncthreads();
  if (t < 128) {
    float vv = part[0][t] + part[1][t] + bo[t];
    b1[t] = vv;
    tish[c * 128 + t] = vv;
  }
  __syncthreads();
  for (int j = t; j < 896; j += 256) {
    float a = bcat[j];
#pragma unroll 4
    for (int k = 0; k < 128; ++k) a = fmaf(b1[k], Wcat_t[k * 896 + j], a);
    catv[j] = a;
  }
  __syncthreads();
  if (t < 128) {
    float td = catv[t];
    float r = 1.f / (1.f + expf(-(catv[128 + t] + catv[512 + t])));
    float zz = 1.f / (1.f + expf(-(catv[256 + t] + catv[640 + t])));
    float nn = tanhf(catv[384 + t] + r * catv[768 + t]);
    float cn = (1.f - zz) * nn + zz * td;
    ccell[c * 128 + t] = cn;
    b0[t] = cn;
  }
  __syncthreads();
  if (gatWt) {
    float ps = 0.f;
    const float* wp = gatWt + (size_t)ks * 64 * 128 + tf;
#pragma unroll 4
    for (int k = 0; k < 64; ++k) ps = fmaf(b0[ks * 64 + k], wp[k * 128], ps);
    part[ks][tf] = ps;
    __syncthreads();
    if (t < 128) {
      float hp = part[0][t] + part[1][t];
      hprojc[c * 128 + t] = f2b(hp);
      float pss = hp * avs[t], pdd = hp * avd[t];
      pss += __shfl_xor(pss, 1); pss += __shfl_xor(pss, 2); pss += __shfl_xor(pss, 4); pss += __shfl_xor(pss, 8);
      pdd += __shfl_xor(pdd, 1); pdd += __shfl_xor(pdd, 2); pdd += __shfl_xor(pdd, 4); pdd += __shfl_xor(pdd, 8);
      if ((t & 15) == 0) {
        a_s2[c * 8 + (t >> 4)] = pss;
        a_d2[c * 8 + (t >> 4)] = pdd;
      }
    }
  }
}

// ---------------- parallel dual-pool partials: grid PB blocks ----------------
__global__ __launch_bounds__(256) void hg_pool(const float* __restrict__ ccell2, const float* __restrict__ tish,
                                               const int* __restrict__ cnt, float* __restrict__ part) {
  int b = blockIdx.x, t = threadIdx.x;
  int c0 = b * (C / PB);
  if (t < 128) {
    float sm = 0.f, mx = -INFINITY;
#pragma unroll 4
    for (int i = 0; i < C / PB; ++i) {
      int c = c0 + i;
      float vv = ccell2[c * 128 + t];
      int n = cnt[c];
      sm += (float)n * vv;
      if (n > 0) mx = fmaxf(mx, vv);
    }
    part[b * 512 + t] = sm;
    part[b * 512 + 128 + t] = mx;
  } else {
    int tt = t - 128;
    float sm = 0.f, mx = -INFINITY;
#pragma unroll 4
    for (int i = 0; i < C / PB; ++i) {
      int c = c0 + i;
      float vv = tish[c * 128 + tt];
      sm += vv;
      mx = fmaxf(mx, vv);
    }
    part[b * 512 + 256 + tt] = sm;
    part[b * 512 + 384 + tt] = mx;
  }
}

// ---------------- classifier MLP (merges pool partials) ----------------
__global__ __launch_bounds__(256) void hg_mlp(const float* __restrict__ part, const float* __restrict__ Wc1t,
                                              const float* __restrict__ bc1, const float* __restrict__ Wc2t,
                                              const float* __restrict__ bc2, const float* __restrict__ Wc3,
                                              const float* __restrict__ bc3, float* __restrict__ outp) {
  __shared__ float emb[512], h1s[256], h2s[128];
  int t = threadIdx.x;
  if (t < 128) {
    float sm = 0.f, mx = -INFINITY;
#pragma unroll
    for (int b = 0; b < PB; ++b) {
      sm += part[b * 512 + t];
      mx = fmaxf(mx, part[b * 512 + 128 + t]);
    }
    emb[t] = sm / (float)N;
    emb[128 + t] = mx;
  } else {
    int tt = t - 128;
    float sm = 0.f, mx = -INFINITY;
#pragma unroll
    for (int b = 0; b < PB; ++b) {
      sm += part[b * 512 + 256 + tt];
      mx = fmaxf(mx, part[b * 512 + 384 + tt]);
    }
    emb[256 + tt] = sm * (1.f / (float)C);
    emb[384 + tt] = mx;
  }
  __syncthreads();
  float a = bc1[t];
#pragma unroll 4
  for (int kk = 0; kk < 512; ++kk) a = fmaf(emb[kk], Wc1t[kk * 256 + t], a);
  h1s[t] = fmaxf(a, 0.f);
  __syncthreads();
  if (t < 128) {
    float a2 = bc2[t];
#pragma unroll 4
    for (int kk = 0; kk < 256; ++kk) a2 = fmaf(h1s[kk], Wc2t[kk * 128 + t], a2);
    h2s[t] = fmaxf(a2, 0.f);
  }
  __syncthreads();
  if (t < 4) {
    float o = bc3[t];
    for (int kk = 0; kk < 128; ++kk) o = fmaf(h2s[kk], Wc3[t * 128 + kk], o);
    outp[t] = o;
  }
}

// ---------------- host launcher ----------------
extern "C" void kernel_launch(void* const* d_in, const int* in_sizes, int n_in,
                              void* d_out, int out_size, void* d_ws, size_t ws_size,
                              hipStream_t stream) {
  (void)in_sizes; (void)n_in; (void)out_size; (void)ws_size;
  const float* feat  = (const float*)d_in[0];
  const int*   eidx  = (const int*)d_in[1];
  const int*   lab   = (const int*)d_in[2];
  const int*   tidx  = (const int*)d_in[3];
  const float* Wcp   = (const float*)d_in[4];
  const float* bcp   = (const float*)d_in[5];
  const float* Wtp   = (const float*)d_in[6];
  const float* btp   = (const float*)d_in[7];
  const float* gatW  = (const float*)d_in[8];
  const float* gasrc = (const float*)d_in[9];
  const float* gadst = (const float*)d_in[10];
  const float* gatb  = (const float*)d_in[11];
  const float* gcnW  = (const float*)d_in[12];
  const float* gcnb  = (const float*)d_in[13];
  const float* buWq  = (const float*)d_in[14];
  const float* buWk  = (const float*)d_in[15];
  const float* buWv  = (const float*)d_in[16];
  const float* bubq  = (const float*)d_in[17];
  const float* bubk  = (const float*)d_in[18];
  const float* bubv  = (const float*)d_in[19];
  const float* buWo  = (const float*)d_in[20];
  const float* bubo  = (const float*)d_in[21];
  const float* tdWv  = (const float*)d_in[22];
  const float* tdbv  = (const float*)d_in[23];
  const float* tdWo  = (const float*)d_in[24];
  const float* tdbo  = (const float*)d_in[25];
  const float* Wih   = (const float*)d_in[26];
  const float* bih   = (const float*)d_in[27];
  const float* Whh   = (const float*)d_in[28];
  const float* bhh   = (const float*)d_in[29];
  const float* Wc1   = (const float*)d_in[30];
  const float* bc1   = (const float*)d_in[31];
  const float* Wc2   = (const float*)d_in[32];
  const float* bc2   = (const float*)d_in[33];
  const float* Wc3   = (const float*)d_in[34];
  const float* bc3   = (const float*)d_in[35];
  float* outp = (float*)d_out;

  const int* csrc = eidx;
  const int* cdst = eidx + E;
  const int* tsrc = tidx;
  const int* tdst = tidx + ET;

  char* w = (char*)d_ws;
  auto alloc = [&](size_t bytes) -> void* {
    void* p = (void*)w;
    w += (bytes + 255) & ~(size_t)255;
    return p;
  };
  char* cnt0 = w;
  int* deg_cell = (int*)alloc((size_t)N * 4);
  int* cur_cell = (int*)alloc((size_t)N * 4);
  int* clu_cnt  = (int*)alloc((size_t)C * 4);
  int* clu_cur  = (int*)alloc((size_t)C * 4);
  size_t cntBytes = (size_t)(w - cnt0);
  int* off_cell = (int*)alloc((size_t)(N + 1) * 4);
  int* btot     = (int*)alloc(64 * 4);
  int* csr      = (int*)alloc((size_t)E * 4);
  int* clu_off  = (int*)alloc((size_t)(C + 1) * 4);
  int* clu_list = (int*)alloc((size_t)N * 4);
  int* toff     = (int*)alloc((size_t)(C + 1) * 4);
  int* tlist    = (int*)alloc((size_t)ET * 4);
  float* dinv   = (float*)alloc((size_t)C * 4);
  unsigned short* buf1 = (unsigned short*)alloc((size_t)N * 128 * 2);  // bf16 cell_h
  unsigned short* buf2 = (unsigned short*)alloc((size_t)N * 128 * 2);  // bf16 hproj
  float* a_s    = (float*)alloc((size_t)N * 8 * 4);
  float* a_d    = (float*)alloc((size_t)N * 8 * 4);
  float* s_att  = (float*)alloc((size_t)N * 8 * 4);
  float* tish   = (float*)alloc((size_t)C * 128 * 4);
  float* qkb    = (float*)alloc((size_t)C * 8 * 128 * 4);
  float* qbb    = (float*)alloc((size_t)C * 8 * 4);
  float* ccell  = (float*)alloc((size_t)C * 128 * 4);
  unsigned short* hprojc = (unsigned short*)alloc((size_t)C * 128 * 2);
  float* a_sc   = (float*)alloc((size_t)C * 8 * 4);
  float* a_dc   = (float*)alloc((size_t)C * 8 * 4);
  float* pm     = (float*)alloc((size_t)C * SPL * 8 * 4);
  float* pz     = (float*)alloc((size_t)C * SPL * 8 * 4);
  float* pmacc  = (float*)alloc((size_t)C * SPL * 8 * 128 * 4);
  float* poolp  = (float*)alloc((size_t)PB * 512 * 4);
  float* A_td   = (float*)alloc(128 * 128 * 4);
  float* Wcat_t = (float*)alloc(128 * 896 * 4);
  float* bcat   = (float*)alloc(896 * 4);
  short* Wcompb = (short*)alloc(128 * 256 * 2);   // bf16 composite weight [j][k]
  float* bcomp  = (float*)alloc(128 * 4);
  float* Wtpt   = (float*)alloc(256 * 128 * 4);
  float* g1t    = (float*)alloc(128 * 128 * 4);
  float* g2t    = (float*)alloc(128 * 128 * 4);
  float* Wqt    = (float*)alloc(128 * 128 * 4);
  float* Wot    = (float*)alloc(128 * 128 * 4);
  float* gatW2t = (float*)alloc(128 * 128 * 4);
  float* Wc1t   = (float*)alloc(512 * 256 * 4);
  float* Wc2t   = (float*)alloc(256 * 128 * 4);

  hipMemsetAsync(cnt0, 0, cntBytes, stream);

  hg_hist<<<(E + 255) / 256, 256, 0, stream>>>(cdst, deg_cell, lab, clu_cnt);
  hg_scan1<<<NB, 256, 0, stream>>>(deg_cell, off_cell, btot, N);
  hg_scan2_setup<<<3, 256, 0, stream>>>(btot, off_cell, clu_cnt, clu_off, tsrc, tdst, toff, tlist, dinv);
  hg_scan3<<<NB, 256, 0, stream>>>(off_cell, btot, N);
  hg_scatter<<<(E + 255) / 256, 256, 0, stream>>>(csrc, cdst, off_cell, cur_cell, csr,
                                                  lab, clu_off, clu_cur, clu_list);

  PrepArgs pa;
  pa.j[0] = {Wtp,            Wtpt,   128, 256, 128};
  pa.j[1] = {gcnW,           g1t,    128, 128, 128};
  pa.j[2] = {gcnW + 128*128, g2t,    128, 128, 128};
  pa.j[3] = {buWq,           Wqt,    128, 128, 128};
  pa.j[4] = {buWo,           Wot,    128, 128, 128};
  pa.j[5] = {gatW + 128*128, gatW2t, 128, 128, 128};
  pa.j[6] = {Wc1,            Wc1t,   256, 512, 256};
  pa.j[7] = {Wc2,            Wc2t,   128, 256, 128};
  pa.gatW1 = gatW; pa.Wcp = Wcp; pa.bcp = bcp; pa.Wcompb = Wcompb; pa.bcomp = bcomp;
  pa.tdWo = tdWo; pa.tdWv = tdWv; pa.tdbv = tdbv; pa.tdbo = tdbo;
  pa.A_td = A_td; pa.Wcat_t = Wcat_t; pa.bcat = bcat;
  hg_prep1<<<dim3(128, 10), 256, 0, stream>>>(pa);
  hg_pc2b<<<384, 256, 0, stream>>>(Wih, bih, Whh, bhh, A_td, Wcat_t, bcat);

  const int RT = (N + 127) / 128;  // 469 row tiles
  hg_gemm_coef<<<RT + C, 256, 0, stream>>>(feat, N, RT, Wcompb, bcomp, buf2, gasrc, gadst, a_s, a_d,
                                           clu_list, clu_off, Wtpt, btp, tish);
  // ---- layer 1 ----
  hg_gcn_q<<<C, 128, 0, stream>>>(tish, toff, tlist, dinv, g1t, gcnb, Wqt, bubq, buWk, bubk, qkb, qbb);
  hg_gat_agg<<<NWG_AGG, 256, 0, stream>>>(buf2, a_s, a_d, nullptr, off_cell, csr, gatb, buf1,
                                          qkb, qbb, lab, clu_list, s_att, N);
  hg_bu_part<<<dim3(C, SPL), 256, 0, stream>>>(s_att, buf1, clu_list, clu_off, pm, pz, pmacc);
  hg_bu_chain<<<C, 256, 0, stream>>>(pm, pz, pmacc, buWv, bubv, Wot, bubo, Wcat_t, bcat,
                                     gatW2t, gasrc + 128, gadst + 128, tish, ccell, hprojc, a_sc, a_dc);
  // ---- layer 2 ----
  hg_gcn_q<<<C, 128, 0, stream>>>(tish, toff, tlist, dinv, g2t, gcnb + 128, Wqt, bubq, buWk, bubk, qkb, qbb);
  hg_gat_agg<<<NWG_AGG, 256, 0, stream>>>(hprojc, a_sc, a_dc, lab, off_cell, csr, gatb + 128, buf1,
                                          qkb, qbb, lab, clu_list, s_att, N);
  hg_bu_part<<<dim3(C, SPL), 256, 0, stream>>>(s_att, buf1, clu_list, clu_off, pm, pz, pmacc);
  hg_bu_chain<<<C, 256, 0, stream>>>(pm, pz, pmacc, buWv, bubv, Wot, bubo, Wcat_t, bcat,
                                     nullptr, nullptr, nullptr, tish, ccell, nullptr, nullptr, nullptr);

  hg_pool<<<PB, 256, 0, stream>>>(ccell, tish, clu_cnt, poolp);
  hg_mlp<<<1, 256, 0, stream>>>(poolp, Wc1t, bc1, Wc2t, bc2, Wc3, bc3, outp);
}

// Round 15
// 539.227 us; speedup vs baseline: 1.0771x; 1.0068x over previous
//
#include <hip/hip_runtime.h>
#include <math.h>

constexpr int N  = 60000;
constexpr int F  = 256;
constexpr int H  = 128;
constexpr int C  = 256;
constexpr int E  = 600000;
constexpr int ET = 1500;
constexpr int NB = (N + 1023) / 1024;  // 59 scan blocks
constexpr int SPL = 8;                 // bu softmax splits per cluster
constexpr int PB  = 16;                // pooling blocks

typedef __attribute__((ext_vector_type(8))) short short8;
typedef __attribute__((ext_vector_type(4))) float f32x4;

__device__ __forceinline__ unsigned short f2b(float f) {  // fp32 -> bf16 (RNE)
  unsigned int u = __float_as_uint(f);
  return (unsigned short)((u + 0x7FFFu + ((u >> 16) & 1u)) >> 16);
}
__device__ __forceinline__ float b2f(unsigned short b) {
  return __uint_as_float(((unsigned int)b) << 16);
}

// ---------------- histograms (cell-dst degree + cluster counts) ----------------
__global__ void hg_hist(const int* __restrict__ cdst, int* __restrict__ deg,
                        const int* __restrict__ lab, int* __restrict__ ccnt) {
  int e = blockIdx.x * 256 + threadIdx.x;
  if (e < E) atomicAdd(&deg[cdst[e]], 1);
  if (e < N) atomicAdd(&ccnt[lab[e]], 1);
}

// ---------------- multi-block scan ----------------
__global__ __launch_bounds__(256) void hg_scan1(const int* __restrict__ deg, int* __restrict__ off,
                                                int* __restrict__ btot, int n) {
  int b = blockIdx.x, t = threadIdx.x;
  int i0 = b * 1024 + t * 4;
  __shared__ int sums[256];
  int d0 = 0, d1 = 0, d2 = 0, d3 = 0;
  if (i0 + 3 < n) {
    int4 dd = *(const int4*)&deg[i0];
    d0 = dd.x; d1 = dd.y; d2 = dd.z; d3 = dd.w;
  } else {
    if (i0     < n) d0 = deg[i0];
    if (i0 + 1 < n) d1 = deg[i0 + 1];
    if (i0 + 2 < n) d2 = deg[i0 + 2];
    if (i0 + 3 < n) d3 = deg[i0 + 3];
  }
  int s = d0 + d1 + d2 + d3;
  sums[t] = s;
  __syncthreads();
  for (int ofs = 1; ofs < 256; ofs <<= 1) {
    int v = (t >= ofs) ? sums[t - ofs] : 0;
    __syncthreads();
    sums[t] += v;
    __syncthreads();
  }
  int excl = sums[t] - s;
  if (t == 255) btot[b] = sums[t];
  int run = excl;
  if (i0     < n) off[i0]     = run; run += d0;
  if (i0 + 1 < n) off[i0 + 1] = run; run += d1;
  if (i0 + 2 < n) off[i0 + 2] = run; run += d2;
  if (i0 + 3 < n) off[i0 + 3] = run;
}

// block0: scan of btot; block1: cluster-count scan; block2: tissue CSR + dinv
__global__ __launch_bounds__(256) void hg_scan2_setup(int* __restrict__ btot, int* __restrict__ off,
                                                      const int* __restrict__ ccnt, int* __restrict__ coff,
                                                      const int* __restrict__ tsrc, const int* __restrict__ tdst,
                                                      int* __restrict__ toff, int* __restrict__ tlist,
                                                      float* __restrict__ dinv) {
  __shared__ int sa[256], sb[256], sc2[256];
  int t = threadIdx.x;
  if (blockIdx.x == 0) {
    if (t < 64) sa[t] = (t < NB) ? btot[t] : 0;
    __syncthreads();
    if (t == 0) {
      int r = 0;
      for (int i = 0; i < NB; ++i) { int v = sa[i]; sa[i] = r; r += v; }
      off[N] = r;
    }
    __syncthreads();
    if (t < NB) btot[t] = sa[t];
  } else if (blockIdx.x == 1) {
    int v0 = ccnt[t];
    sa[t] = v0;
    __syncthreads();
    for (int ofs = 1; ofs < 256; ofs <<= 1) {
      int v = (t >= ofs) ? sa[t - ofs] : 0;
      __syncthreads();
      sa[t] += v;
      __syncthreads();
    }
    coff[t + 1] = sa[t];
    if (t == 0) coff[0] = 0;
  } else {
    sa[t] = 0;
    __syncthreads();
    for (int e = t; e < ET; e += 256) atomicAdd(&sa[tdst[e]], 1);
    __syncthreads();
    int v = sa[t];
    dinv[t] = rsqrtf((float)(v + 1));
    sb[t] = v;
    __syncthreads();
    for (int ofs = 1; ofs < 256; ofs <<= 1) {
      int u = (t >= ofs) ? sb[t - ofs] : 0;
      __syncthreads();
      sb[t] += u;
      __syncthreads();
    }
    toff[t + 1] = sb[t];
    if (t == 0) toff[0] = 0;
    sc2[t] = sb[t] - v;
    __syncthreads();
    for (int e = t; e < ET; e += 256) {
      int d = tdst[e];
      int p = atomicAdd(&sc2[d], 1);
      tlist[p] = tsrc[e];
    }
  }
}

__global__ void hg_scan3(int* __restrict__ off, const int* __restrict__ btot, int n) {
  int b = blockIdx.x;
  int addv = btot[b];
  int i0 = b * 1024 + threadIdx.x * 4;
#pragma unroll
  for (int r = 0; r < 4; ++r)
    if (i0 + r < n) off[i0 + r] += addv;
}

// merged: cell-edge CSR scatter + cluster-list scatter
__global__ void hg_scatter(const int* __restrict__ csrc, const int* __restrict__ cdst,
                           const int* __restrict__ off, int* __restrict__ cur, int* __restrict__ csr,
                           const int* __restrict__ lab, const int* __restrict__ coff,
                           int* __restrict__ ccur, int* __restrict__ list) {
  int e = blockIdx.x * 256 + threadIdx.x;
  if (e < E) {
    int d = cdst[e];
    int p = atomicAdd(&cur[d], 1);
    csr[off[d] + p] = csrc[e];
  }
  if (e < N) {
    int c = lab[e];
    int p = atomicAdd(&ccur[c], 1);
    list[coff[c] + p] = e;
  }
}

// ---------------- prep: 8 transposes + pc0(bf16) + pc1 (grid y = job) ----------------
struct TJob { const float* src; float* dst; int SR; int SC; int dld; };
struct PrepArgs {
  TJob j[8];
  const float* gatW1; const float* Wcp; const float* bcp; short* Wcompb; float* bcomp;
  const float* tdWo; const float* tdWv; const float* tdbv; const float* tdbo;
  float* A_td; float* Wcat_t; float* bcat;
};

__global__ __launch_bounds__(256) void hg_prep1(PrepArgs a) {
  int y = blockIdx.y, t = threadIdx.x;
  if (y < 8) {
    TJob jb = a.j[y];
    int total = jb.SR * jb.SC;
    for (int idx = blockIdx.x * 256 + t; idx < total; idx += gridDim.x * 256) {
      int r = idx / jb.SC, c = idx - r * jb.SC;
      jb.dst[(size_t)c * jb.dld + r] = jb.src[idx];
    }
  } else if (y == 8) {
    // pc0: Wcomp[j][k] = sum_m gatW1[j][m]*Wcp[m][k]  (bf16, j-major for MFMA B frags)
    int j = blockIdx.x, k = t;
    float acc = 0.f;
#pragma unroll 4
    for (int m = 0; m < 128; ++m) acc = fmaf(a.gatW1[j * 128 + m], a.Wcp[m * 256 + k], acc);
    a.Wcompb[(size_t)j * 256 + k] = (short)f2b(acc);
    if (k == 0) {
      float b = 0.f;
      for (int m = 0; m < 128; ++m) b = fmaf(a.gatW1[j * 128 + m], a.bcp[m], b);
      a.bcomp[j] = b;
    }
  } else if (blockIdx.x < 64) {
    int j = blockIdx.x * 2 + (t >> 7), k = t & 127;
    float acc = 0.f;
#pragma unroll 4
    for (int p = 0; p < 128; ++p) acc = fmaf(a.tdWo[j * 128 + p], a.tdWv[p * 128 + k], acc);
    a.A_td[j * 128 + k] = acc;
    a.Wcat_t[k * 896 + j] = acc;
    if (k == 0) {
      float b = 0.f;
      for (int p = 0; p < 128; ++p) b = fmaf(a.tdWo[j * 128 + p], a.tdbv[p], b);
      a.bcat[j] = b + a.tdbo[j];
    }
  }
}

__global__ __launch_bounds__(256) void hg_pc2b(const float* __restrict__ Wih, const float* __restrict__ bih,
                                               const float* __restrict__ Whh, const float* __restrict__ bhh,
                                               const float* __restrict__ A_td, float* __restrict__ Wcat_t,
                                               float* __restrict__ bcat) {
  int jj = blockIdx.x * 2 + (threadIdx.x >> 7), k = threadIdx.x & 127;
  const float* coef;
  float extra, bb;
  int dcol, j;
  if (jj < 384) {
    j = jj; coef = Wih + (size_t)j * 256; extra = Wih[(size_t)j * 256 + 128 + k]; dcol = 128 + j; bb = bih[j];
  } else {
    j = jj - 384; coef = Whh + (size_t)j * 128; extra = 0.f; dcol = 512 + j; bb = bhh[j];
  }
  float a = 0.f;
#pragma unroll 4
  for (int m = 0; m < 128; ++m) a = fmaf(coef[m], A_td[m * 128 + k], a);
  Wcat_t[k * 896 + dcol] = a + extra;
  if (k == 0) {
    float b = 0.f;
    for (int m = 0; m < 128; ++m) b = fmaf(coef[m], bcat[m], b);
    bcat[dcol] = b + bb;
  }
}

// ---------------- MFMA bf16 GEMM (K=256, tile 128x128, no LDS) + GAT-coef epilogue ----------------
__global__ __launch_bounds__(256, 3) void hg_gemm_coef(
    const float* __restrict__ A, int M, int rtiles,
    const short* __restrict__ Wb,          // bf16 [128][256] j-major
    const float* __restrict__ bias,
    unsigned short* __restrict__ outp,     // bf16 [M][128]
    const float* __restrict__ avs, const float* __restrict__ avd,
    float* __restrict__ o_s, float* __restrict__ o_d,
    const int* __restrict__ list, const int* __restrict__ coff,
    const float* __restrict__ Wtpt, const float* __restrict__ btp, float* __restrict__ tish) {
  __shared__ float mrow[256];
  const int t = threadIdx.x;

  if (blockIdx.x >= rtiles) {
    // ---- tissue init: per-cluster mean + projection (fp32) ----
    int c = blockIdx.x - rtiles;
    int s0 = coff[c], n = coff[c + 1] - s0;
    float acc = 0.f;
#pragma unroll 4
    for (int i = 0; i < n; ++i) acc += A[(size_t)list[s0 + i] * F + t];
    mrow[t] = acc / fmaxf((float)n, 1.f);
    __syncthreads();
    if (t < 128) {
      float a = btp[t];
#pragma unroll 4
      for (int k = 0; k < 256; ++k) a = fmaf(mrow[k], Wtpt[k * 128 + t], a);
      tish[c * 128 + t] = a;
    }
    return;
  }

  const int w = t >> 6, l = t & 63;
  const int li = l & 15, lk = l >> 4;   // li: row/col within 16-tile, lk: k-group
  const int m0 = blockIdx.x * 128 + w * 32;

  f32x4 zero = {0.f, 0.f, 0.f, 0.f};
  f32x4 acc[2][8];
#pragma unroll
  for (int rt = 0; rt < 2; ++rt)
#pragma unroll
    for (int ct = 0; ct < 8; ++ct) acc[rt][ct] = zero;

  const int r0 = m0 + li, r1 = m0 + 16 + li;
  const bool v0 = r0 < M, v1 = r1 < M;
  const float* a0p = A + (size_t)r0 * 256 + lk * 8;
  const float* a1p = A + (size_t)r1 * 256 + lk * 8;

  for (int kc = 0; kc < 256; kc += 32) {
    short8 bf[8];
#pragma unroll
    for (int ct = 0; ct < 8; ++ct)
      bf[ct] = *(const short8*)&Wb[(size_t)(ct * 16 + li) * 256 + kc + lk * 8];
    short8 af0 = {0, 0, 0, 0, 0, 0, 0, 0};
    short8 af1 = {0, 0, 0, 0, 0, 0, 0, 0};
    if (v0) {
      float4 x = *(const float4*)(a0p + kc);
      float4 y = *(const float4*)(a0p + kc + 4);
      af0[0] = (short)f2b(x.x); af0[1] = (short)f2b(x.y); af0[2] = (short)f2b(x.z); af0[3] = (short)f2b(x.w);
      af0[4] = (short)f2b(y.x); af0[5] = (short)f2b(y.y); af0[6] = (short)f2b(y.z); af0[7] = (short)f2b(y.w);
    }
    if (v1) {
      float4 x = *(const float4*)(a1p + kc);
      float4 y = *(const float4*)(a1p + kc + 4);
      af1[0] = (short)f2b(x.x); af1[1] = (short)f2b(x.y); af1[2] = (short)f2b(x.z); af1[3] = (short)f2b(x.w);
      af1[4] = (short)f2b(y.x); af1[5] = (short)f2b(y.y); af1[6] = (short)f2b(y.z); af1[7] = (short)f2b(y.w);
    }
#pragma unroll
    for (int ct = 0; ct < 8; ++ct) {
      acc[0][ct] = __builtin_amdgcn_mfma_f32_16x16x32_bf16(af0, bf[ct], acc[0][ct], 0, 0, 0);
      acc[1][ct] = __builtin_amdgcn_mfma_f32_16x16x32_bf16(af1, bf[ct], acc[1][ct], 0, 0, 0);
    }
  }

  // epilogue: bias, bf16 store, per-head coef dots (row-outer so o_s/o_d writes coalesce)
#pragma unroll
  for (int rt = 0; rt < 2; ++rt) {
#pragma unroll
    for (int r = 0; r < 4; ++r) {
      int gm = m0 + rt * 16 + lk * 4 + r;
      float psv[8], pdv[8];
#pragma unroll
      for (int ct = 0; ct < 8; ++ct) {
        float v = acc[rt][ct][r] + bias[ct * 16 + li];
        if (gm < M) outp[(size_t)gm * 128 + ct * 16 + li] = f2b(v);
        float ps = v * avs[ct * 16 + li], pd = v * avd[ct * 16 + li];
        ps += __shfl_xor(ps, 1); ps += __shfl_xor(ps, 2); ps += __shfl_xor(ps, 4); ps += __shfl_xor(ps, 8);
        pd += __shfl_xor(pd, 1); pd += __shfl_xor(pd, 2); pd += __shfl_xor(pd, 4); pd += __shfl_xor(pd, 8);
        psv[ct] = ps;
        pdv[ct] = pd;
      }
      if (li == 0 && gm < M) {
        float* osp = o_s + (size_t)gm * 8;
        float* odp = o_d + (size_t)gm * 8;
        *(float4*)osp       = make_float4(psv[0], psv[1], psv[2], psv[3]);
        *(float4*)(osp + 4) = make_float4(psv[4], psv[5], psv[6], psv[7]);
        *(float4*)odp       = make_float4(pdv[0], pdv[1], pdv[2], pdv[3]);
        *(float4*)(odp + 4) = make_float4(pdv[4], pdv[5], pdv[6], pdv[7]);
      }
    }
  }
}

// ---------------- GAT aggregation: one WAVE per node, bf16 gathers, XCD-swizzled grid ----------------
// Scores are ~0.05-scale weight dots (|s| << 80), so exp() is overflow-safe without
// max subtraction; softmax ratio is exact up to fp32 rounding. Single-pass score phase.
#define GMAXE 64
constexpr int NWG_AGG = (N + 3) / 4;  // 15000, divisible by 8
__global__ __launch_bounds__(256) void hg_gat_agg(
    const unsigned short* __restrict__ hproj, const float* __restrict__ a_s,
    const float* __restrict__ a_d, const int* __restrict__ remap,
    const int* __restrict__ off, const int* __restrict__ csr,
    const float* __restrict__ bias, unsigned short* __restrict__ outh,
    const float* __restrict__ qk, const float* __restrict__ qb,
    const int* __restrict__ lab, const int* __restrict__ nodelist,
    float* __restrict__ satt, int nNodes) {
  const int wid = threadIdx.x >> 6;
  const int l = threadIdx.x & 63;
  // bijective XCD-aware swizzle: consecutive swizzled blocks stay on one XCD's L2
  const int bidx = blockIdx.x;
  const int sb = (NWG_AGG % 8 == 0) ? ((bidx & 7) * (NWG_AGG / 8) + (bidx >> 3)) : bidx;
  const int gid = sb * 4 + wid;
  __shared__ int srcs_s[4][GMAXE];
  __shared__ float w_s[4][GMAXE][8];
  if (gid >= nNodes) return;
  const int node = nodelist[gid];
  int* srcs = srcs_s[wid];
  float (*wls)[8] = w_s[wid];
  const int o0 = off[node], deg = off[node + 1] - o0;
  const int cl = lab[node];
  const int dl = remap ? cl : node;
  const int hsc = l & 7;
  const int q4 = l & 31;
  const int sub = l >> 5;
  const int hq = q4 >> 2;
  const float adh = a_d[dl * 8 + hsc];
  const float ash = a_s[dl * 8 + hsc];
  float zsc = 0.f;
  float4 acc = make_float4(0.f, 0.f, 0.f, 0.f);
  const ushort4* hp4 = (const ushort4*)hproj;  // 4 bf16 per element

  for (int cb = 0; cb < deg; cb += GMAXE) {
    const int len = min(GMAXE, deg - cb);
    if (l < len) {
      int s = csr[o0 + cb + l];
      srcs[l] = remap ? remap[s] : s;
    }
    asm volatile("s_waitcnt lgkmcnt(0)" ::: "memory");
    // single-pass scores: leaky_relu -> exp -> LDS + z accumulate (no max needed)
    float zc = 0.f;
    for (int base = 0; base < len; base += 8) {
      int e = base + (l >> 3);
      if (e < len) {
        float sc = a_s[srcs[e] * 8 + hsc] + adh;
        sc = sc > 0.f ? sc : 0.2f * sc;
        float wv = __expf(sc);
        wls[e][hsc] = wv;
        zc += wv;
      }
    }
    asm volatile("s_waitcnt lgkmcnt(0)" ::: "memory");
    zc += __shfl_xor(zc, 8); zc += __shfl_xor(zc, 16); zc += __shfl_xor(zc, 32);
    zsc += zc;
    for (int e = sub; e < len; e += 2) {
      float wv = wls[e][hq];
      ushort4 hv = hp4[(size_t)srcs[e] * 32 + q4];
      acc.x = fmaf(wv, b2f(hv.x), acc.x);
      acc.y = fmaf(wv, b2f(hv.y), acc.y);
      acc.z = fmaf(wv, b2f(hv.z), acc.z);
      acc.w = fmaf(wv, b2f(hv.w), acc.w);
    }
  }
  // self-loop
  float ssl = ash + adh;
  ssl = ssl > 0.f ? ssl : 0.2f * ssl;
  float wsl = __expf(ssl);
  zsc += wsl;
  float wsa = __shfl(wsl, hq);
  float zh = __shfl(zsc, hq);
  acc.x += __shfl_xor(acc.x, 32);
  acc.y += __shfl_xor(acc.y, 32);
  acc.z += __shfl_xor(acc.z, 32);
  acc.w += __shfl_xor(acc.w, 32);
  ushort4 hvs = hp4[(size_t)dl * 32 + q4];
  acc.x = fmaf(wsa, b2f(hvs.x), acc.x);
  acc.y = fmaf(wsa, b2f(hvs.y), acc.y);
  acc.z = fmaf(wsa, b2f(hvs.z), acc.z);
  acc.w = fmaf(wsa, b2f(hvs.w), acc.w);
  float inv = 1.f / zh;
  float4 bv4 = *(const float4*)&bias[q4 * 4];
  float4 o;
  o.x = acc.x * inv + bv4.x;
  o.y = acc.y * inv + bv4.y;
  o.z = acc.z * inv + bv4.z;
  o.w = acc.w * inv + bv4.w;
  o.x = o.x > 0.f ? o.x : __expf(o.x) - 1.f;
  o.y = o.y > 0.f ? o.y : __expf(o.y) - 1.f;
  o.z = o.z > 0.f ? o.z : __expf(o.z) - 1.f;
  o.w = o.w > 0.f ? o.w : __expf(o.w) - 1.f;
  if (sub == 0) {
    ushort4 ov = make_ushort4(f2b(o.x), f2b(o.y), f2b(o.z), f2b(o.w));
    ((ushort4*)outh)[(size_t)node * 32 + q4] = ov;
  }

  // s_att epilogue (qk L2-hot via clu_list ordering + XCD swizzle)
  const float4* qk4 = (const float4*)(qk + (size_t)cl * 1024);
  float p0, p1, p2, p3;
  {
    float4 qv0 = qk4[(sub * 4 + 0) * 32 + q4];
    float4 qv1 = qk4[(sub * 4 + 1) * 32 + q4];
    float4 qv2 = qk4[(sub * 4 + 2) * 32 + q4];
    float4 qv3 = qk4[(sub * 4 + 3) * 32 + q4];
    p0 = o.x * qv0.x + o.y * qv0.y + o.z * qv0.z + o.w * qv0.w;
    p1 = o.x * qv1.x + o.y * qv1.y + o.z * qv1.z + o.w * qv1.w;
    p2 = o.x * qv2.x + o.y * qv2.y + o.z * qv2.z + o.w * qv2.w;
    p3 = o.x * qv3.x + o.y * qv3.y + o.z * qv3.z + o.w * qv3.w;
  }
  int b4f = (l >> 4) & 1, b3f = (l >> 3) & 1;
  float snd0 = b4f ? p0 : p2, snd1 = b4f ? p1 : p3;
  float kp0  = b4f ? p2 : p0, kp1  = b4f ? p3 : p1;
  kp0 += __shfl_xor(snd0, 16);
  kp1 += __shfl_xor(snd1, 16);
  float snd = b3f ? kp0 : kp1;
  float kp  = b3f ? kp1 : kp0;
  kp += __shfl_xor(snd, 8);
  kp += __shfl_xor(kp, 4);
  kp += __shfl_xor(kp, 2);
  kp += __shfl_xor(kp, 1);
  int h = sub * 4 + b4f * 2 + b3f;
  if ((l & 7) == 0) satt[(size_t)node * 8 + h] = kp + qb[cl * 8 + h];
}

// ---------------- tissue GCN + q projection + qk/qb tables ----------------
__global__ __launch_bounds__(128) void hg_gcn_q(const float* __restrict__ tin, const int* __restrict__ toff,
                                                const int* __restrict__ tlist, const float* __restrict__ dinv,
                                                const float* __restrict__ gt, const float* __restrict__ gcnb,
                                                const float* __restrict__ Wqt, const float* __restrict__ bq,
                                                const float* __restrict__ Wk, const float* __restrict__ bk,
                                                float* __restrict__ qk, float* __restrict__ qb) {
  int c = blockIdx.x, t = threadIdx.x;
  __shared__ float xa[128], trow[128], qrow[128];
  float dc = dinv[c];
  float acc = tin[c * 128 + t] * dc * dc;
  int s0 = toff[c], s1 = toff[c + 1];
  for (int i = s0; i < s1; ++i) {
    int s = tlist[i];
    acc = fmaf(tin[s * 128 + t], dinv[s] * dc, acc);
  }
  xa[t] = acc;
  __syncthreads();
  float th = 0.f;
#pragma unroll 4
  for (int k = 0; k < 128; ++k) th = fmaf(xa[k], gt[k * 128 + t], th);
  float vv = fmaxf(th + gcnb[t], 0.f);
  trow[t] = vv;
  __syncthreads();
  float qa = bq[t];
#pragma unroll 4
  for (int k = 0; k < 128; ++k) qa = fmaf(trow[k], Wqt[k * 128 + t], qa);
  qrow[t] = qa * 0.25f;  // 1/sqrt(DH)
  __syncthreads();
#pragma unroll
  for (int h = 0; h < 8; ++h) {
    float s = 0.f;
#pragma unroll
    for (int j = 0; j < 16; ++j) s = fmaf(Wk[(size_t)(h * 16 + j) * 128 + t], qrow[h * 16 + j], s);
    qk[((size_t)c * 8 + h) * 128 + t] = s;
  }
  if (t < 8) {
    float s = 0.f;
#pragma unroll
    for (int j = 0; j < 16; ++j) s = fmaf(qrow[t * 16 + j], bk[t * 16 + j], s);
    qb[c * 8 + t] = s;
  }
}

// ---------------- bu softmax partials: grid (C, SPL), bf16 gathers ----------------
__global__ __launch_bounds__(256) void hg_bu_part(
    const float* __restrict__ s_att, const unsigned short* __restrict__ hcell,
    const int* __restrict__ list, const int* __restrict__ coff,
    float* __restrict__ pm, float* __restrict__ pz, float* __restrict__ pmacc) {
  int c = blockIdx.x, sp = blockIdx.y, t = threadIdx.x;
  int s0 = coff[c], n = coff[c + 1] - s0;
  int chunk = (n + SPL - 1) / SPL;
  int b0 = min(n, sp * chunk), b1 = min(n, b0 + chunk);
  int cnt = b1 - b0;
  int tf = t & 127, half = t >> 7;
  __shared__ float red[32][8];
  __shared__ float mh[8];
  __shared__ int cells[64];
  __shared__ float wl[64][8];
  __shared__ float msh[8][128];
  int g = t >> 3, h8 = t & 7;
  float lm = -INFINITY;
  for (int i = g; i < cnt; i += 32) lm = fmaxf(lm, s_att[(size_t)list[s0 + b0 + i] * 8 + h8]);
  red[g][h8] = lm;
  __syncthreads();
  if (t < 8) {
    float m2 = -INFINITY;
#pragma unroll
    for (int i = 0; i < 32; ++i) m2 = fmaxf(m2, red[i][t]);
    mh[t] = m2;
  }
  __syncthreads();
  const float mloc = mh[t & 7];
  float zp = 0.f;
  float macc[8] = {0.f, 0.f, 0.f, 0.f, 0.f, 0.f, 0.f, 0.f};
  for (int cb = 0; cb < cnt; cb += 64) {
    int len = min(64, cnt - cb);
    if (t < len) cells[t] = list[s0 + b0 + cb + t];
    __syncthreads();
#pragma unroll
    for (int p = 0; p < 2; ++p) {
      int e = p * 32 + (t >> 3);
      if (e < len) {
        float w = __expf(s_att[(size_t)cells[e] * 8 + (t & 7)] - mloc);
        wl[e][t & 7] = w;
        zp += w;
      }
    }
    __syncthreads();
    for (int e = half; e < len; e += 2) {
      float x = b2f(hcell[(size_t)cells[e] * 128 + tf]);
      float4 w0 = *(const float4*)&wl[e][0];
      float4 w1 = *(const float4*)&wl[e][4];
      macc[0] = fmaf(w0.x, x, macc[0]);
      macc[1] = fmaf(w0.y, x, macc[1]);
      macc[2] = fmaf(w0.z, x, macc[2]);
      macc[3] = fmaf(w0.w, x, macc[3]);
      macc[4] = fmaf(w1.x, x, macc[4]);
      macc[5] = fmaf(w1.y, x, macc[5]);
      macc[6] = fmaf(w1.z, x, macc[6]);
      macc[7] = fmaf(w1.w, x, macc[7]);
    }
    __syncthreads();
  }
  red[t >> 3][t & 7] = zp;
  __syncthreads();
  int pidx = (c * SPL + sp) * 8;
  if (t < 8) {
    float z = 0.f;
#pragma unroll
    for (int i = 0; i < 32; ++i) z += red[i][t];
    pz[pidx + t] = z;
    pm[pidx + t] = mh[t];
  }
  if (half) {
#pragma unroll
    for (int h = 0; h < 8; ++h) msh[h][tf] = macc[h];
  }
  __syncthreads();
  if (!half) {
#pragma unroll
    for (int h = 0; h < 8; ++h) pmacc[(size_t)(pidx + h) * 128 + tf] = macc[h] + msh[h][tf];
  }
}

// ---------------- fused cluster chain: merge partials, Wv, Wo, td+GRU, gates, next GAT proj ----------------
__global__ __launch_bounds__(256) void hg_bu_chain(
    const float* __restrict__ pm, const float* __restrict__ pz, const float* __restrict__ pmacc,
    const float* __restrict__ Wv, const float* __restrict__ bv,
    const float* __restrict__ Wot, const float* __restrict__ bo,
    const float* __restrict__ Wcat_t, const float* __restrict__ bcat,
    const float* __restrict__ gatWt, const float* __restrict__ avs, const float* __restrict__ avd,
    float* __restrict__ tish, float* __restrict__ ccell,
    unsigned short* __restrict__ hprojc, float* __restrict__ a_s2, float* __restrict__ a_d2) {
  int c = blockIdx.x, t = threadIdx.x;
  int tf = t & 127, half = t >> 7;
  __shared__ float mh[8], zh[8];
  __shared__ float sscale[SPL][8];
  __shared__ float msh[8][128];
  __shared__ float b0[128], b1[128], part[2][128], catv[896];
  const int pbase = c * SPL * 8;
  if (t < 8) {
    float mg = -INFINITY;
#pragma unroll
    for (int s = 0; s < SPL; ++s) mg = fmaxf(mg, pm[pbase + s * 8 + t]);
    mh[t] = mg;
  }
  __syncthreads();
  if (t < SPL * 8) {
    int s = t >> 3, h = t & 7;
    float ms = pm[pbase + s * 8 + h];
    sscale[s][h] = (ms > -1e37f) ? __expf(ms - mh[h]) : 0.f;
  }
  __syncthreads();
  if (t < 8) {
    float z = 0.f;
#pragma unroll
    for (int s = 0; s < SPL; ++s) z += pz[pbase + s * 8 + t] * sscale[s][t];
    zh[t] = (z > 0.f) ? 1.f / z : 0.f;
  }
  __syncthreads();
#pragma unroll
  for (int hh = 0; hh < 4; ++hh) {
    int h = half * 4 + hh;
    float a = 0.f;
#pragma unroll
    for (int s = 0; s < SPL; ++s)
      a = fmaf(pmacc[(size_t)(pbase + s * 8 + h) * 128 + tf], sscale[s][h], a);
    msh[h][tf] = a * zh[h];
  }
  __syncthreads();
  {
    int h = tf >> 4;
    float ps = 0.f;
    const float* wp = Wv + (size_t)tf * 128 + half * 64;
    const float* mp = &msh[h][half * 64];
#pragma unroll 4
    for (int k = 0; k < 64; ++k) ps = fmaf(wp[k], mp[k], ps);
    part[half][tf] = ps;
  }
  __syncthreads();
  if (t < 128) b0[t] = part[0][t] + part[1][t] + bv[t];
  __syncthreads();
  int ks = half;
  {
    float ps = 0.f;
    const float* wp = Wot + (size_t)ks * 64 * 128 + tf;
#pragma unroll 4
    for (int k = 0; k < 64; ++k) ps = fmaf(b0[ks * 64 + k], wp[k * 128], ps);
    part[ks][tf] = ps;
  }
  __syncthreads();
  if (t < 128) {
    float vv = part[0][t] + part[1][t] + bo[t];
    b1[t] = vv;
    tish[c * 128 + t] = vv;
  }
  __syncthreads();
  for (int j = t; j < 896; j += 256) {
    float a = bcat[j];
#pragma unroll 4
    for (int k = 0; k < 128; ++k) a = fmaf(b1[k], Wcat_t[k * 896 + j], a);
    catv[j] = a;
  }
  __syncthreads();
  if (t < 128) {
    float td = catv[t];
    float r = 1.f / (1.f + expf(-(catv[128 + t] + catv[512 + t])));
    float zz = 1.f / (1.f + expf(-(catv[256 + t] + catv[640 + t])));
    float nn = tanhf(catv[384 + t] + r * catv[768 + t]);
    float cn = (1.f - zz) * nn + zz * td;
    ccell[c * 128 + t] = cn;
    b0[t] = cn;
  }
  __syncthreads();
  if (gatWt) {
    float ps = 0.f;
    const float* wp = gatWt + (size_t)ks * 64 * 128 + tf;
#pragma unroll 4
    for (int k = 0; k < 64; ++k) ps = fmaf(b0[ks * 64 + k], wp[k * 128], ps);
    part[ks][tf] = ps;
    __syncthreads();
    if (t < 128) {
      float hp = part[0][t] + part[1][t];
      hprojc[c * 128 + t] = f2b(hp);
      float pss = hp * avs[t], pdd = hp * avd[t];
      pss += __shfl_xor(pss, 1); pss += __shfl_xor(pss, 2); pss += __shfl_xor(pss, 4); pss += __shfl_xor(pss, 8);
      pdd += __shfl_xor(pdd, 1); pdd += __shfl_xor(pdd, 2); pdd += __shfl_xor(pdd, 4); pdd += __shfl_xor(pdd, 8);
      if ((t & 15) == 0) {
        a_s2[c * 8 + (t >> 4)] = pss;
        a_d2[c * 8 + (t >> 4)] = pdd;
      }
    }
  }
}

// ---------------- parallel dual-pool partials: grid PB blocks ----------------
__global__ __launch_bounds__(256) void hg_pool(const float* __restrict__ ccell2, const float* __restrict__ tish,
                                               const int* __restrict__ cnt, float* __restrict__ part) {
  int b = blockIdx.x, t = threadIdx.x;
  int c0 = b * (C / PB);
  if (t < 128) {
    float sm = 0.f, mx = -INFINITY;
#pragma unroll 4
    for (int i = 0; i < C / PB; ++i) {
      int c = c0 + i;
      float vv = ccell2[c * 128 + t];
      int n = cnt[c];
      sm += (float)n * vv;
      if (n > 0) mx = fmaxf(mx, vv);
    }
    part[b * 512 + t] = sm;
    part[b * 512 + 128 + t] = mx;
  } else {
    int tt = t - 128;
    float sm = 0.f, mx = -INFINITY;
#pragma unroll 4
    for (int i = 0; i < C / PB; ++i) {
      int c = c0 + i;
      float vv = tish[c * 128 + tt];
      sm += vv;
      mx = fmaxf(mx, vv);
    }
    part[b * 512 + 256 + tt] = sm;
    part[b * 512 + 384 + tt] = mx;
  }
}

// ---------------- classifier MLP (merges pool partials) ----------------
__global__ __launch_bounds__(256) void hg_mlp(const float* __restrict__ part, const float* __restrict__ Wc1t,
                                              const float* __restrict__ bc1, const float* __restrict__ Wc2t,
                                              const float* __restrict__ bc2, const float* __restrict__ Wc3,
                                              const float* __restrict__ bc3, float* __restrict__ outp) {
  __shared__ float emb[512], h1s[256], h2s[128];
  int t = threadIdx.x;
  if (t < 128) {
    float sm = 0.f, mx = -INFINITY;
#pragma unroll
    for (int b = 0; b < PB; ++b) {
      sm += part[b * 512 + t];
      mx = fmaxf(mx, part[b * 512 + 128 + t]);
    }
    emb[t] = sm / (float)N;
    emb[128 + t] = mx;
  } else {
    int tt = t - 128;
    float sm = 0.f, mx = -INFINITY;
#pragma unroll
    for (int b = 0; b < PB; ++b) {
      sm += part[b * 512 + 256 + tt];
      mx = fmaxf(mx, part[b * 512 + 384 + tt]);
    }
    emb[256 + tt] = sm * (1.f / (float)C);
    emb[384 + tt] = mx;
  }
  __syncthreads();
  float a = bc1[t];
#pragma unroll 4
  for (int kk = 0; kk < 512; ++kk) a = fmaf(emb[kk], Wc1t[kk * 256 + t], a);
  h1s[t] = fmaxf(a, 0.f);
  __syncthreads();
  if (t < 128) {
    float a2 = bc2[t];
#pragma unroll 4
    for (int kk = 0; kk < 256; ++kk) a2 = fmaf(h1s[kk], Wc2t[kk * 128 + t], a2);
    h2s[t] = fmaxf(a2, 0.f);
  }
  __syncthreads();
  if (t < 4) {
    float o = bc3[t];
    for (int kk = 0; kk < 128; ++kk) o = fmaf(h2s[kk], Wc3[t * 128 + kk], o);
    outp[t] = o;
  }
}

// ---------------- host launcher ----------------
extern "C" void kernel_launch(void* const* d_in, const int* in_sizes, int n_in,
                              void* d_out, int out_size, void* d_ws, size_t ws_size,
                              hipStream_t stream) {
  (void)in_sizes; (void)n_in; (void)out_size; (void)ws_size;
  const float* feat  = (const float*)d_in[0];
  const int*   eidx  = (const int*)d_in[1];
  const int*   lab   = (const int*)d_in[2];
  const int*   tidx  = (const int*)d_in[3];
  const float* Wcp   = (const float*)d_in[4];
  const float* bcp   = (const float*)d_in[5];
  const float* Wtp   = (const float*)d_in[6];
  const float* btp   = (const float*)d_in[7];
  const float* gatW  = (const float*)d_in[8];
  const float* gasrc = (const float*)d_in[9];
  const float* gadst = (const float*)d_in[10];
  const float* gatb  = (const float*)d_in[11];
  const float* gcnW  = (const float*)d_in[12];
  const float* gcnb  = (const float*)d_in[13];
  const float* buWq  = (const float*)d_in[14];
  const float* buWk  = (const float*)d_in[15];
  const float* buWv  = (const float*)d_in[16];
  const float* bubq  = (const float*)d_in[17];
  const float* bubk  = (const float*)d_in[18];
  const float* bubv  = (const float*)d_in[19];
  const float* buWo  = (const float*)d_in[20];
  const float* bubo  = (const float*)d_in[21];
  const float* tdWv  = (const float*)d_in[22];
  const float* tdbv  = (const float*)d_in[23];
  const float* tdWo  = (const float*)d_in[24];
  const float* tdbo  = (const float*)d_in[25];
  const float* Wih   = (const float*)d_in[26];
  const float* bih   = (const float*)d_in[27];
  const float* Whh   = (const float*)d_in[28];
  const float* bhh   = (const float*)d_in[29];
  const float* Wc1   = (const float*)d_in[30];
  const float* bc1   = (const float*)d_in[31];
  const float* Wc2   = (const float*)d_in[32];
  const float* bc2   = (const float*)d_in[33];
  const float* Wc3   = (const float*)d_in[34];
  const float* bc3   = (const float*)d_in[35];
  float* outp = (float*)d_out;

  const int* csrc = eidx;
  const int* cdst = eidx + E;
  const int* tsrc = tidx;
  const int* tdst = tidx + ET;

  char* w = (char*)d_ws;
  auto alloc = [&](size_t bytes) -> void* {
    void* p = (void*)w;
    w += (bytes + 255) & ~(size_t)255;
    return p;
  };
  char* cnt0 = w;
  int* deg_cell = (int*)alloc((size_t)N * 4);
  int* cur_cell = (int*)alloc((size_t)N * 4);
  int* clu_cnt  = (int*)alloc((size_t)C * 4);
  int* clu_cur  = (int*)alloc((size_t)C * 4);
  size_t cntBytes = (size_t)(w - cnt0);
  int* off_cell = (int*)alloc((size_t)(N + 1) * 4);
  int* btot     = (int*)alloc(64 * 4);
  int* csr      = (int*)alloc((size_t)E * 4);
  int* clu_off  = (int*)alloc((size_t)(C + 1) * 4);
  int* clu_list = (int*)alloc((size_t)N * 4);
  int* toff     = (int*)alloc((size_t)(C + 1) * 4);
  int* tlist    = (int*)alloc((size_t)ET * 4);
  float* dinv   = (float*)alloc((size_t)C * 4);
  unsigned short* buf1 = (unsigned short*)alloc((size_t)N * 128 * 2);  // bf16 cell_h
  unsigned short* buf2 = (unsigned short*)alloc((size_t)N * 128 * 2);  // bf16 hproj
  float* a_s    = (float*)alloc((size_t)N * 8 * 4);
  float* a_d    = (float*)alloc((size_t)N * 8 * 4);
  float* s_att  = (float*)alloc((size_t)N * 8 * 4);
  float* tish   = (float*)alloc((size_t)C * 128 * 4);
  float* qkb    = (float*)alloc((size_t)C * 8 * 128 * 4);
  float* qbb    = (float*)alloc((size_t)C * 8 * 4);
  float* ccell  = (float*)alloc((size_t)C * 128 * 4);
  unsigned short* hprojc = (unsigned short*)alloc((size_t)C * 128 * 2);
  float* a_sc   = (float*)alloc((size_t)C * 8 * 4);
  float* a_dc   = (float*)alloc((size_t)C * 8 * 4);
  float* pm     = (float*)alloc((size_t)C * SPL * 8 * 4);
  float* pz     = (float*)alloc((size_t)C * SPL * 8 * 4);
  float* pmacc  = (float*)alloc((size_t)C * SPL * 8 * 128 * 4);
  float* poolp  = (float*)alloc((size_t)PB * 512 * 4);
  float* A_td   = (float*)alloc(128 * 128 * 4);
  float* Wcat_t = (float*)alloc(128 * 896 * 4);
  float* bcat   = (float*)alloc(896 * 4);
  short* Wcompb = (short*)alloc(128 * 256 * 2);   // bf16 composite weight [j][k]
  float* bcomp  = (float*)alloc(128 * 4);
  float* Wtpt   = (float*)alloc(256 * 128 * 4);
  float* g1t    = (float*)alloc(128 * 128 * 4);
  float* g2t    = (float*)alloc(128 * 128 * 4);
  float* Wqt    = (float*)alloc(128 * 128 * 4);
  float* Wot    = (float*)alloc(128 * 128 * 4);
  float* gatW2t = (float*)alloc(128 * 128 * 4);
  float* Wc1t   = (float*)alloc(512 * 256 * 4);
  float* Wc2t   = (float*)alloc(256 * 128 * 4);

  hipMemsetAsync(cnt0, 0, cntBytes, stream);

  hg_hist<<<(E + 255) / 256, 256, 0, stream>>>(cdst, deg_cell, lab, clu_cnt);
  hg_scan1<<<NB, 256, 0, stream>>>(deg_cell, off_cell, btot, N);
  hg_scan2_setup<<<3, 256, 0, stream>>>(btot, off_cell, clu_cnt, clu_off, tsrc, tdst, toff, tlist, dinv);
  hg_scan3<<<NB, 256, 0, stream>>>(off_cell, btot, N);
  hg_scatter<<<(E + 255) / 256, 256, 0, stream>>>(csrc, cdst, off_cell, cur_cell, csr,
                                                  lab, clu_off, clu_cur, clu_list);

  PrepArgs pa;
  pa.j[0] = {Wtp,            Wtpt,   128, 256, 128};
  pa.j[1] = {gcnW,           g1t,    128, 128, 128};
  pa.j[2] = {gcnW + 128*128, g2t,    128, 128, 128};
  pa.j[3] = {buWq,           Wqt,    128, 128, 128};
  pa.j[4] = {buWo,           Wot,    128, 128, 128};
  pa.j[5] = {gatW + 128*128, gatW2t, 128, 128, 128};
  pa.j[6] = {Wc1,            Wc1t,   256, 512, 256};
  pa.j[7] = {Wc2,            Wc2t,   128, 256, 128};
  pa.gatW1 = gatW; pa.Wcp = Wcp; pa.bcp = bcp; pa.Wcompb = Wcompb; pa.bcomp = bcomp;
  pa.tdWo = tdWo; pa.tdWv = tdWv; pa.tdbv = tdbv; pa.tdbo = tdbo;
  pa.A_td = A_td; pa.Wcat_t = Wcat_t; pa.bcat = bcat;
  hg_prep1<<<dim3(128, 10), 256, 0, stream>>>(pa);
  hg_pc2b<<<384, 256, 0, stream>>>(Wih, bih, Whh, bhh, A_td, Wcat_t, bcat);

  const int RT = (N + 127) / 128;  // 469 row tiles
  hg_gemm_coef<<<RT + C, 256, 0, stream>>>(feat, N, RT, Wcompb, bcomp, buf2, gasrc, gadst, a_s, a_d,
                                           clu_list, clu_off, Wtpt, btp, tish);
  // ---- layer 1 ----
  hg_gcn_q<<<C, 128, 0, stream>>>(tish, toff, tlist, dinv, g1t, gcnb, Wqt, bubq, buWk, bubk, qkb, qbb);
  hg_gat_agg<<<NWG_AGG, 256, 0, stream>>>(buf2, a_s, a_d, nullptr, off_cell, csr, gatb, buf1,
                                          qkb, qbb, lab, clu_list, s_att, N);
  hg_bu_part<<<dim3(C, SPL), 256, 0, stream>>>(s_att, buf1, clu_list, clu_off, pm, pz, pmacc);
  hg_bu_chain<<<C, 256, 0, stream>>>(pm, pz, pmacc, buWv, bubv, Wot, bubo, Wcat_t, bcat,
                                     gatW2t, gasrc + 128, gadst + 128, tish, ccell, hprojc, a_sc, a_dc);
  // ---- layer 2 ----
  hg_gcn_q<<<C, 128, 0, stream>>>(tish, toff, tlist, dinv, g2t, gcnb + 128, Wqt, bubq, buWk, bubk, qkb, qbb);
  hg_gat_agg<<<NWG_AGG, 256, 0, stream>>>(hprojc, a_sc, a_dc, lab, off_cell, csr, gatb + 128, buf1,
                                          qkb, qbb, lab, clu_list, s_att, N);
  hg_bu_part<<<dim3(C, SPL), 256, 0, stream>>>(s_att, buf1, clu_list, clu_off, pm, pz, pmacc);
  hg_bu_chain<<<C, 256, 0, stream>>>(pm, pz, pmacc, buWv, bubv, Wot, bubo, Wcat_t, bcat,
                                     nullptr, nullptr, nullptr, tish, ccell, nullptr, nullptr, nullptr);

  hg_pool<<<PB, 256, 0, stream>>>(ccell, tish, clu_cnt, poolp);
  hg_mlp<<<1, 256, 0, stream>>>(poolp, Wc1t, bc1, Wc2t, bc2, Wc3, bc3, outp);
}